// Round 10
// baseline (219.336 us; speedup 1.0000x reference)
//
#include <hip/hip_runtime.h>
#include <hip/hip_bf16.h>

typedef __hip_bfloat16 bf16;
typedef __attribute__((ext_vector_type(8))) short bf16x8;
typedef __attribute__((ext_vector_type(4))) float f32x4;

// Problem constants: B=4, H=W=60, C=256, HEADS=8, hd=32, WS=7 -> 9x9 windows/batch,
// 324 windows, 49 q/window, key window 27x27=729 gathered from the 27x27 stride-3
// grid. KEY IDENTITY: token = kk + C with C = 81*wh + 3*ww - 336 -> contiguous
// token slice; invalid keys killed by precomputed ADDITIVE mask (-30000).
// All external I/O f32; staging bf16. Softmax in log2 domain (q pre-scaled by
// hd^-0.5*log2(e); exp = v_exp_f32).
//
// Verified MFMA lane mapping (16x16x32 bf16, rounds 3-9):
//   A-frag: lane(li=lane&15, lg=lane>>4) holds A[row=li][k=lg*8+e (mod 32)]
//   B-frag: lane holds B[col=li][k=lg*8+e]
//   C/D   : [row=lg*4+r][col=li]
// Swapped QK^T: S^T = mfma(A=K, B=Q) -> lane holds S[key=t*16+lg*4+r][q=li].
// PV key<->k-slot permutation key(e)=(2c+(e>>2))*16+lg*4+(e&3) applied identically
// to the P B-frag (cvt_pk dwords) and the V A-frag reads (2x8B per frag).
// Round 10: mlp back to 16 tokens x 900 blocks (round-4 geometry) with the
// fragment-packed weights (round-5) -> half the VGPR, 2x the blocks.

#define QSCALE 0.25505402616302864f  // (1/sqrt(32)) * log2(e)

__device__ __forceinline__ bf16 f2bf(float f){ return __float2bfloat16(f); }
__device__ __forceinline__ unsigned short f2bfu(float f){
  __hip_bfloat16 h = __float2bfloat16(f);
  return *(unsigned short*)&h;
}
__device__ __forceinline__ float fexp2(float x){
  float r; asm("v_exp_f32 %0, %1" : "=v"(r) : "v"(x)); return r;
}
__device__ __forceinline__ unsigned cvtpk(float lo, float hi){
  unsigned r; asm("v_cvt_pk_bf16_f32 %0, %1, %2" : "=v"(r) : "v"(lo), "v"(hi));
  return r;
}

// ---------------- K0: pack weights (fragment order) + vbufT pads + attn mask
__global__ __launch_bounds__(256) void wt_kernel(
    const float* __restrict__ fc1_w, const float* __restrict__ fc2_w,
    const float* __restrict__ proj_w, const float* __restrict__ q_w,
    const float* __restrict__ kv_w,
    bf16* __restrict__ W1F, bf16* __restrict__ W2F, bf16* __restrict__ PWF,
    bf16* __restrict__ QWF, bf16* __restrict__ KVF, bf16* __restrict__ vbufT,
    float* __restrict__ maskbuf){
  int gid = blockIdx.x*256 + threadIdx.x;
  if (gid < 262144){               // W1F: K=256 (kc<8), N=1024 (nt<64)
    int e=gid&7, lane=(gid>>3)&63, kc=(gid>>9)&7, nt=gid>>12;
    int li=lane&15, lg=lane>>4;
    W1F[gid] = f2bf(fc1_w[(size_t)(kc*32+lg*8+e)*1024 + nt*16+li]);
  } else if (gid < 524288){        // W2F: K=1024 (kc<32), N=256 (nt<16)
    int o = gid - 262144;
    int e=o&7, lane=(o>>3)&63, kc=(o>>9)&31, nt=o>>14;
    int li=lane&15, lg=lane>>4;
    W2F[o] = f2bf(fc2_w[(size_t)(kc*32+lg*8+e)*256 + nt*16+li]);
  } else if (gid < 589824){        // PWF: K=256 (kc<8), N=256 (nt<16)
    int o = gid - 524288;
    int e=o&7, lane=(o>>3)&63, kc=(o>>9)&7, nt=o>>12;
    int li=lane&15, lg=lane>>4;
    PWF[o] = f2bf(proj_w[(size_t)(kc*32+lg*8+e)*256 + nt*16+li]);
  } else if (gid < 655360){        // QWF: K=256, N=256, scaled by QSCALE
    int o = gid - 589824;
    int e=o&7, lane=(o>>3)&63, kc=(o>>9)&7, nt=o>>12;
    int li=lane&15, lg=lane>>4;
    QWF[o] = f2bf(q_w[(size_t)(kc*32+lg*8+e)*256 + nt*16+li] * QSCALE);
  } else if (gid < 786432){        // KVF: K=256, N=512 (nt<32)
    int o = gid - 655360;
    int e=o&7, lane=(o>>3)&63, kc=(o>>9)&7, nt=o>>12;
    int li=lane&15, lg=lane>>4;
    KVF[o] = f2bf(kv_w[(size_t)(kc*32+lg*8+e)*512 + nt*16+li]);
  } else {
    int idx = gid - 786432;
    if (idx < 7168){
      // vbufT row pads [row*736+729, +7): attn OOB V reads must be finite
      int row = idx/7, p = idx - row*7;
      vbufT[(size_t)row*736 + 729 + p] = f2bf(0.f);
    } else if (idx < 7680){
      vbufT[(size_t)1024*736 + (idx-7168)] = f2bf(0.f);  // hi-guard
    } else {
      // additive attn mask[81][768]: local key index -> 0 or -30000
      int o = idx - 7680;            // 0..62207
      int wi2 = o / 768, local = o - wi2*768;
      int wh2 = wi2/9, ww2 = wi2 - wh2*9;
      int C2 = 81*wh2 + 3*ww2 - 336;
      int off2 = C2 & 7;
      int kk = local - off2;
      bool valid = ((unsigned)kk < 729u);
      int kr = valid ? kk/27 : 0;
      int kc2 = kk - kr*27;
      int gr = wh2*3 - 12 + kr, gc = ww2*3 - 12 + kc2;
      valid = valid && ((unsigned)gr < 27u) && ((unsigned)gc < 27u)
                    && !(gr >= 24 && gc >= 24);
      maskbuf[(size_t)wi2*768 + local] = valid ? 0.f : -30000.f;
    }
  }
}

// ---------------- K1: MFMA LN(y)+kv proj -> kbuf (key-major) + vbufT (dim-major)
__global__ __launch_bounds__(256) void kv_kernel(
    const float* __restrict__ y, const float* __restrict__ g,
    const float* __restrict__ bb, const bf16* __restrict__ KVF,
    bf16* __restrict__ kbuf, bf16* __restrict__ vbufT){
  __shared__ __align__(16) unsigned short xn[16*256];  // swizzled bf16, 8 KB
  int tid = threadIdx.x, wid = tid>>6, lane = tid&63;
  int li = lane&15, lg = lane>>4;
  int tok0 = blockIdx.x * 16;
  {
    float4 g4 = ((const float4*)g)[lane];
    float4 b4 = ((const float4*)bb)[lane];
    #pragma unroll
    for (int tt=0; tt<4; tt++){
      int t = wid*4 + tt;
      int gtok = tok0 + t;
      float4 v = make_float4(0.f,0.f,0.f,0.f);
      if (gtok < 2916) v = ((const float4*)(y + (size_t)gtok*256))[lane];
      float s = v.x+v.y+v.z+v.w, ss = v.x*v.x+v.y*v.y+v.z*v.z+v.w*v.w;
      #pragma unroll
      for (int off=32; off; off>>=1){ s += __shfl_xor(s,off); ss += __shfl_xor(ss,off); }
      float mean = s*(1.f/256.f);
      float var  = fmaxf(ss*(1.f/256.f) - mean*mean, 0.f);
      float inv  = rsqrtf(var + 1e-5f);
      ushort4 pk;
      pk.x = f2bfu((v.x-mean)*inv*g4.x+b4.x);
      pk.y = f2bfu((v.y-mean)*inv*g4.y+b4.y);
      pk.z = f2bfu((v.z-mean)*inv*g4.z+b4.z);
      pk.w = f2bfu((v.w-mean)*inv*g4.w+b4.w);
      int idx = (t*256 + lane*4) ^ ((t&7)<<3);
      *(ushort4*)&xn[idx] = pk;
    }
  }
  __syncthreads();
  bf16x8 a[8];
  #pragma unroll
  for (int ks=0; ks<8; ks++){
    int idx = (li*256 + ks*32 + lg*8) ^ ((li&7)<<3);
    a[ks] = *(const bf16x8*)&xn[idx];
  }
  #pragma unroll
  for (int nn=0; nn<8; nn++){
    int ntg = wid*8 + nn;
    const bf16* wp = KVF + (size_t)ntg*4096 + lane*8;
    f32x4 acc = {0.f,0.f,0.f,0.f};
    #pragma unroll
    for (int ks=0; ks<8; ks++){
      bf16x8 bfrag = *(const bf16x8*)(wp + ks*512);
      acc = __builtin_amdgcn_mfma_f32_16x16x32_bf16(a[ks], bfrag, acc, 0, 0, 0);
    }
    int col = ntg*16 + li;
    #pragma unroll
    for (int r=0; r<4; r++){
      int tok = tok0 + lg*4 + r;
      if (tok < 2916){
        if (col < 256){
          kbuf[(size_t)tok*256 + col] = f2bf(acc[r]);
        } else {
          int b2 = (tok>=729) + (tok>=1458) + (tok>=2187);
          int ltok = tok - b2*729;
          vbufT[(size_t)(b2*256 + col-256)*736 + ltok] = f2bf(acc[r]);
        }
      }
    }
  }
}

// ---------------- K2: MFMA per-window LN(xw)+q proj (scale in QWF) ---------
__global__ __launch_bounds__(256) void q_kernel(
    const float* __restrict__ x, const float* __restrict__ g,
    const float* __restrict__ bb, const bf16* __restrict__ QWF,
    bf16* __restrict__ qbuf){
  __shared__ __align__(16) unsigned short on[64*256];  // swizzled bf16, 32 KB
  int tid = threadIdx.x, wid = tid>>6, lane = tid&63;
  int li = lane&15, lg = lane>>4;
  int w = blockIdx.x;
  int b = w/81, wi = w - b*81, wh = wi/9, ww = wi - wh*9;
  float4 g4 = ((const float4*)g)[lane];
  float4 b4 = ((const float4*)bb)[lane];
  for (int t=wid; t<64; t+=4){
    float4 v = make_float4(0.f,0.f,0.f,0.f);
    if (t < 49){
      int r = t/7, c = t - r*7;
      int gh = wh*7 + r, gw = ww*7 + c;
      if (gh < 60 && gw < 60)
        v = ((const float4*)(x + (size_t)(b*3600 + gh*60 + gw)*256))[lane];
    }
    float s=v.x+v.y+v.z+v.w, ss=v.x*v.x+v.y*v.y+v.z*v.z+v.w*v.w;
    #pragma unroll
    for (int off=32; off; off>>=1){ s += __shfl_xor(s,off); ss += __shfl_xor(ss,off); }
    float mean = s*(1.f/256.f);
    float var = fmaxf(ss*(1.f/256.f)-mean*mean, 0.f);
    float inv = rsqrtf(var+1e-5f);
    ushort4 pk;
    pk.x = f2bfu((v.x-mean)*inv*g4.x+b4.x);
    pk.y = f2bfu((v.y-mean)*inv*g4.y+b4.y);
    pk.z = f2bfu((v.z-mean)*inv*g4.z+b4.z);
    pk.w = f2bfu((v.w-mean)*inv*g4.w+b4.w);
    int idx = (t*256 + lane*4) ^ ((t&7)<<3);
    *(ushort4*)&on[idx] = pk;
  }
  __syncthreads();
  for (int rt=0; rt<4; rt++){
    bf16x8 a[8];
    #pragma unroll
    for (int ks=0; ks<8; ks++){
      int idx = ((rt*16+li)*256 + ks*32 + lg*8) ^ ((li&7)<<3);
      a[ks] = *(const bf16x8*)&on[idx];
    }
    #pragma unroll
    for (int nt=0; nt<4; nt++){
      int ntg = wid*4 + nt;
      const bf16* wp = QWF + (size_t)ntg*4096 + lane*8;
      f32x4 acc = {0.f,0.f,0.f,0.f};
      #pragma unroll
      for (int ks=0; ks<8; ks++){
        bf16x8 bfrag = *(const bf16x8*)(wp + ks*512);
        acc = __builtin_amdgcn_mfma_f32_16x16x32_bf16(a[ks], bfrag, acc, 0, 0, 0);
      }
      int col = ntg*16 + li;
      #pragma unroll
      for (int r=0; r<4; r++){
        int tok = rt*16 + lg*4 + r;
        if (tok < 49)
          qbuf[((size_t)w*49 + tok)*256 + col] = f2bf(acc[r]);
      }
    }
  }
}

// ---------------- K3: swapped-QK^T attention, LDS-staged K/V (dbuf) --------
__global__ __launch_bounds__(256) void attn_kernel(
    const bf16* __restrict__ qbuf, const bf16* __restrict__ kbuf,
    const bf16* __restrict__ vbufT, const float* __restrict__ maskbuf,
    bf16* __restrict__ obuf){
  // K fragment-order: Kls[buf][kt*512 + lane*8] (ushorts) -> ds_read_b128 lane-linear
  __shared__ __align__(16) unsigned short Kls[2][4096];   // 2 x 8 KB
  // V dim-major, row pitch 136 ushorts (17x16B): Vls[buf][d*136 + key]
  __shared__ __align__(16) unsigned short Vls[2][4352];   // 2 x 8.5 KB

  int tid = threadIdx.x, wid = tid>>6, lane = tid&63;
  int lg = lane>>4, li = lane&15;
  int blk = blockIdx.x;
  int w = blk >> 3, hh = blk & 7;
  int b = w/81, wi = w - b*81, wh = wi/9, ww = wi - wh*9;

  int C  = 81*wh + 3*ww - 336;     // token = kk + C
  int T0 = C & ~7;
  const bf16* kb = kbuf  + (long long)(b*729 + T0)*256 + hh*32;
  const bf16* vbT = vbufT + (long long)(b*256 + hh*32)*736 + T0;
  const float* mk = maskbuf + wi*768;

  // --- staging addressing (loop-invariant) ---
  const bf16* ksrcA = kb + (long long)(2*wid*16 + li)*256 + lg*8;
  const bf16* ksrcB = kb + (long long)((2*wid+1)*16 + li)*256 + lg*8;
  int vrow = tid>>4, vch = tid&15;
  const bf16* vsrcA = vbT + (long long)vrow*736 + vch*8;
  const bf16* vsrcB = vbT + (long long)(vrow+16)*736 + vch*8;

  // Q B-frag: col=q=li, k=dim lg*8+e (zero for pad rows -> s=mask only)
  bf16x8 qf;
  #pragma unroll
  for (int e=0;e<8;e++) qf[e]=0;
  int qrow = wid*16 + li;
  if (qrow < 49)
    qf = *(const bf16x8*)(qbuf + ((size_t)w*49+qrow)*256 + hh*32 + lg*8);

  f32x4 o0 = {0.f,0.f,0.f,0.f}, o1 = {0.f,0.f,0.f,0.f};  // O^T: d=lg*4+r (+16), q=li
  float m = -3.0e38f, l = 0.f;

  // --- prologue: stage tile 0 into buf 0 ---
  {
    uint4 k0 = *(const uint4*)ksrcA;
    uint4 k1 = *(const uint4*)ksrcB;
    uint4 v0 = *(const uint4*)vsrcA;
    uint4 v1 = *(const uint4*)vsrcB;
    *(uint4*)&Kls[0][2*wid*512 + lane*8]     = k0;
    *(uint4*)&Kls[0][(2*wid+1)*512 + lane*8] = k1;
    *(uint4*)&Vls[0][vrow*136 + vch*8]       = v0;
    *(uint4*)&Vls[0][(vrow+16)*136 + vch*8]  = v1;
  }
  __syncthreads();

  for (int tile=0; tile<6; tile++){
    int cur = tile & 1, nxt = cur ^ 1;
    int jbase = tile*128;
    // ---- issue next-tile global loads early (hide under compute) ----
    uint4 nk0, nk1, nv0, nv1;
    if (tile < 5){
      int jn = jbase + 128;
      nk0 = *(const uint4*)(ksrcA + (long long)jn*256);
      nk1 = *(const uint4*)(ksrcB + (long long)jn*256);
      nv0 = *(const uint4*)(vsrcA + jn);
      nv1 = *(const uint4*)(vsrcB + jn);
    }
    // ---- S^T = mfma(K, Q): s[t][r] = S[key=jbase+t*16+lg*4+r][q=li] ----
    f32x4 s[8];
    #pragma unroll
    for (int t=0;t<8;t++){
      bf16x8 kf = *(const bf16x8*)&Kls[cur][t*512 + lane*8];
      f32x4 z = {0.f,0.f,0.f,0.f};
      s[t] = __builtin_amdgcn_mfma_f32_16x16x32_bf16(kf, qf, z, 0, 0, 0);
    }
    // ---- additive mask (precomputed per window; broadcast in lg-group) ----
    #pragma unroll
    for (int t=0;t<8;t++){
      float4 mv = *(const float4*)(mk + jbase + t*16 + lg*4);
      s[t][0] += mv.x; s[t][1] += mv.y; s[t][2] += mv.z; s[t][3] += mv.w;
    }
    // ---- online softmax: lane-local 32 keys + 2 lg-group shuffles ----
    float mt = -3.0e38f;
    #pragma unroll
    for (int t=0;t<8;t++)
      mt = fmaxf(mt, fmaxf(fmaxf(s[t][0], s[t][1]), fmaxf(s[t][2], s[t][3])));
    mt = fmaxf(mt, __shfl_xor(mt, 16));
    mt = fmaxf(mt, __shfl_xor(mt, 32));
    float mn = fmaxf(m, mt);
    float fac = fexp2(m - mn);
    m = mn;
    float ps = 0.f;
    #pragma unroll
    for (int t=0;t<8;t++){
      #pragma unroll
      for (int r=0;r<4;r++){
        float p = fexp2(s[t][r] - mn);
        s[t][r] = p;
        ps += p;
      }
    }
    ps += __shfl_xor(ps, 16);
    ps += __shfl_xor(ps, 32);
    l = l*fac + ps;
    #pragma unroll
    for (int r=0;r<4;r++){ o0[r] *= fac; o1[r] *= fac; }
    // ---- P -> bf16 pairs in-register ----
    unsigned pk[8][2];
    #pragma unroll
    for (int t=0;t<8;t++){
      pk[t][0] = cvtpk(s[t][0], s[t][1]);
      pk[t][1] = cvtpk(s[t][2], s[t][3]);
    }
    // ---- O^T += mfma(A=V^T, B=P); V frags from LDS (2x8B, 2-way max) ----
    #pragma unroll
    for (int c=0;c<4;c++){
      union { unsigned u[4]; bf16x8 v; } pb, va, vc;
      pb.u[0]=pk[2*c][0];   pb.u[1]=pk[2*c][1];
      pb.u[2]=pk[2*c+1][0]; pb.u[3]=pk[2*c+1][1];
      const unsigned short* p0 = &Vls[cur][li*136 + c*32 + lg*4];
      const unsigned short* p1 = &Vls[cur][(li+16)*136 + c*32 + lg*4];
      uint2 a0 = *(const uint2*)p0, a1 = *(const uint2*)(p0+16);
      uint2 c0 = *(const uint2*)p1, c1 = *(const uint2*)(p1+16);
      va.u[0]=a0.x; va.u[1]=a0.y; va.u[2]=a1.x; va.u[3]=a1.y;
      vc.u[0]=c0.x; vc.u[1]=c0.y; vc.u[2]=c1.x; vc.u[3]=c1.y;
      o0 = __builtin_amdgcn_mfma_f32_16x16x32_bf16(va.v, pb.v, o0, 0, 0, 0);
      o1 = __builtin_amdgcn_mfma_f32_16x16x32_bf16(vc.v, pb.v, o1, 0, 0, 0);
    }
    // ---- write staged data to next buffer, then barrier ----
    if (tile < 5){
      *(uint4*)&Kls[nxt][2*wid*512 + lane*8]     = nk0;
      *(uint4*)&Kls[nxt][(2*wid+1)*512 + lane*8] = nk1;
      *(uint4*)&Vls[nxt][vrow*136 + vch*8]       = nv0;
      *(uint4*)&Vls[nxt][(vrow+16)*136 + vch*8]  = nv1;
    }
    __syncthreads();
  }

  // ---- epilogue: lane owns q=qrow, dims lg*4+r and 16+lg*4+r ----
  if (qrow < 49){
    float rl = 1.f / l;
    bf16* op = obuf + ((size_t)w*49 + qrow)*256 + hh*32;
    unsigned da0 = cvtpk(o0[0]*rl, o0[1]*rl);
    unsigned da1 = cvtpk(o0[2]*rl, o0[3]*rl);
    unsigned db0 = cvtpk(o1[0]*rl, o1[1]*rl);
    unsigned db1 = cvtpk(o1[2]*rl, o1[3]*rl);
    *(uint2*)(op + lg*4)      = make_uint2(da0, da1);
    *(uint2*)(op + 16 + lg*4) = make_uint2(db0, db1);
  }
}

// ---------------- K4: MFMA out-proj + shortcut + ls1 + window-reverse ------
__global__ __launch_bounds__(256) void proj_kernel(
    const bf16* __restrict__ obuf, const float* __restrict__ x,
    const bf16* __restrict__ PWF, const float* __restrict__ proj_b,
    const float* __restrict__ ls1, float* __restrict__ xobuf){
  __shared__ __align__(16) unsigned short on[64*256];  // swizzled bf16, 32 KB
  int tid = threadIdx.x, wid = tid>>6, lane = tid&63;
  int li = lane&15, lg = lane>>4;
  int w = blockIdx.x;
  int b = w/81, wi = w - b*81, wh = wi/9, ww = wi - wh*9;
  const bf16* ob = obuf + (size_t)w*49*256;
  for (int c=tid; c<2048; c+=256){
    int row = c>>5, col8 = (c&31)*8;
    int idx = (row*256 + col8) ^ ((row&7)<<3);
    uint4 v = make_uint4(0,0,0,0);
    if (row < 49) v = *(const uint4*)(ob + row*256 + col8);
    *(uint4*)&on[idx] = v;
  }
  float pbv[4], l1v[4];
  #pragma unroll
  for (int nt=0; nt<4; nt++){
    int col = wid*64 + nt*16 + li;
    pbv[nt] = proj_b[col];
    l1v[nt] = ls1[col];
  }
  __syncthreads();
  for (int rt=0; rt<4; rt++){
    bf16x8 a[8];
    #pragma unroll
    for (int ks=0; ks<8; ks++){
      int idx = ((rt*16+li)*256 + ks*32 + lg*8) ^ ((li&7)<<3);
      a[ks] = *(const bf16x8*)&on[idx];
    }
    #pragma unroll
    for (int nt=0; nt<4; nt++){
      int nt2 = wid*4 + nt;
      const bf16* wp = PWF + (size_t)nt2*4096 + lane*8;
      f32x4 acc = {0.f,0.f,0.f,0.f};
      #pragma unroll
      for (int ks=0; ks<8; ks++){
        bf16x8 bfrag = *(const bf16x8*)(wp + ks*512);
        acc = __builtin_amdgcn_mfma_f32_16x16x32_bf16(a[ks], bfrag, acc, 0, 0, 0);
      }
      int col = wid*64 + nt*16 + li;
      #pragma unroll
      for (int r=0; r<4; r++){
        int t = rt*16 + lg*4 + r;
        if (t < 49){
          int rr = t/7, cc = t - rr*7;
          int gh = wh*7 + rr, gw = ww*7 + cc;
          if (gh < 60 && gw < 60){
            size_t p = (size_t)(b*3600 + gh*60 + gw)*256 + col;
            xobuf[p] = x[p] + l1v[nt]*(acc[r] + pbv[nt]);
          }
        }
      }
    }
  }
}

// ---------------- K5: MFMA MLP (16 tok x 900 blocks): LN+fc1+GELU+fc2+res --
__global__ __launch_bounds__(256) void mlp_kernel(
    const float* __restrict__ xobuf, const float* __restrict__ g,
    const float* __restrict__ bb, const bf16* __restrict__ W1F,
    const float* __restrict__ fc1_b, const bf16* __restrict__ W2F,
    const float* __restrict__ fc2_b, const float* __restrict__ ls2,
    float* __restrict__ out){
  __shared__ __align__(16) unsigned short xn[16*256];  // swizzled bf16, 8 KB
  __shared__ __align__(16) unsigned short Hls[16*256]; // swizzled bf16, 8 KB
  int tid = threadIdx.x, wid = tid>>6, lane = tid&63;
  int li = lane&15, lg = lane>>4;
  int tok0 = blockIdx.x * 16;
  {
    float4 g4 = ((const float4*)g)[lane];
    float4 b4 = ((const float4*)bb)[lane];
    #pragma unroll
    for (int tt=0; tt<4; tt++){
      int t = wid*4 + tt;
      float4 v = ((const float4*)(xobuf + (size_t)(tok0+t)*256))[lane];
      float s = v.x+v.y+v.z+v.w;
      float ss = v.x*v.x+v.y*v.y+v.z*v.z+v.w*v.w;
      #pragma unroll
      for (int off=32; off; off>>=1){ s += __shfl_xor(s,off); ss += __shfl_xor(ss,off); }
      float mean = s*(1.f/256.f);
      float var = fmaxf(ss*(1.f/256.f)-mean*mean, 0.f);
      float inv = rsqrtf(var+1e-5f);
      ushort4 pk;
      pk.x = f2bfu((v.x-mean)*inv*g4.x+b4.x);
      pk.y = f2bfu((v.y-mean)*inv*g4.y+b4.y);
      pk.z = f2bfu((v.z-mean)*inv*g4.z+b4.z);
      pk.w = f2bfu((v.w-mean)*inv*g4.w+b4.w);
      int idx = (t*256 + lane*4) ^ ((t&7)<<3);
      *(ushort4*)&xn[idx] = pk;
    }
  }
  __syncthreads();
  bf16x8 a1[8];
  #pragma unroll
  for (int ks=0; ks<8; ks++){
    int idx = (li*256 + ks*32 + lg*8) ^ ((li&7)<<3);
    a1[ks] = *(const bf16x8*)&xn[idx];
  }
  f32x4 oacc[4];
  #pragma unroll
  for (int nt=0; nt<4; nt++) oacc[nt] = (f32x4){0.f,0.f,0.f,0.f};

  for (int j=0; j<4; j++){
    // fc1 + GELU -> Hls (wave's 64-col slice of the 256-col j-tile)
    #pragma unroll
    for (int nn=0; nn<4; nn++){
      int ntg = j*16 + wid*4 + nn;
      const bf16* wp = W1F + (size_t)ntg*4096 + lane*8;
      f32x4 hc = {0.f,0.f,0.f,0.f};
      #pragma unroll
      for (int ks=0; ks<8; ks++){
        bf16x8 bfrag = *(const bf16x8*)(wp + ks*512);
        hc = __builtin_amdgcn_mfma_f32_16x16x32_bf16(a1[ks], bfrag, hc, 0, 0, 0);
      }
      float bias = fc1_b[ntg*16 + li];
      int colLoc = wid*64 + nn*16 + li;
      #pragma unroll
      for (int r=0; r<4; r++){
        float h = hc[r] + bias;
        float z = 0.7978845608f*(h + 0.044715f*h*h*h);   // tanh-approx GELU
        z = fminf(fmaxf(z, -15.f), 15.f);
        float e = __expf(2.f*z);
        float gv = 0.5f*h*(1.f + (e-1.f)/(e+1.f));
        int row = lg*4 + r;
        int idx = (row*256 + colLoc) ^ ((row&7)<<3);
        Hls[idx] = f2bfu(gv);
      }
    }
    __syncthreads();
    bf16x8 a2[8];
    #pragma unroll
    for (int ks=0; ks<8; ks++){
      int idx = (li*256 + ks*32 + lg*8) ^ ((li&7)<<3);
      a2[ks] = *(const bf16x8*)&Hls[idx];
    }
    #pragma unroll
    for (int nt=0; nt<4; nt++){
      int nt2 = wid*4 + nt;
      const bf16* wp2 = W2F + ((size_t)nt2*32 + j*8)*512 + lane*8;
      #pragma unroll
      for (int ks=0; ks<8; ks++){
        bf16x8 bfrag = *(const bf16x8*)(wp2 + ks*512);
        oacc[nt] = __builtin_amdgcn_mfma_f32_16x16x32_bf16(a2[ks], bfrag, oacc[nt], 0, 0, 0);
      }
    }
    __syncthreads();
  }
  #pragma unroll
  for (int nt=0; nt<4; nt++){
    int col = wid*64 + nt*16 + li;
    float l2 = ls2[col];
    float cb = fc2_b[col];
    #pragma unroll
    for (int r=0; r<4; r++){
      int tok = tok0 + lg*4 + r;
      size_t p = (size_t)tok*256 + col;
      out[p] = xobuf[p] + l2*(oacc[nt][r] + cb);
    }
  }
}

extern "C" void kernel_launch(void* const* d_in, const int* in_sizes, int n_in,
                              void* d_out, int out_size, void* d_ws, size_t ws_size,
                              hipStream_t stream) {
  (void)in_sizes; (void)n_in; (void)out_size; (void)ws_size;
  const float* x      = (const float*)d_in[0];
  const float* y      = (const float*)d_in[1];
  const float* n1g    = (const float*)d_in[2];
  const float* n1b    = (const float*)d_in[3];
  const float* q_w    = (const float*)d_in[4];
  const float* kv_w   = (const float*)d_in[5];
  const float* proj_w = (const float*)d_in[6];
  const float* proj_b = (const float*)d_in[7];
  const float* n2g    = (const float*)d_in[8];
  const float* n2b    = (const float*)d_in[9];
  const float* fc1_w  = (const float*)d_in[10];
  const float* fc1_b  = (const float*)d_in[11];
  const float* fc2_w  = (const float*)d_in[12];
  const float* fc2_b  = (const float*)d_in[13];
  const float* ls1    = (const float*)d_in[14];
  const float* ls2    = (const float*)d_in[15];

  char* ws = (char*)d_ws;
  // Workspace (24.70 MB):
  //   qbuf  bf16[324*49*256]   @ 0          live K2..K3 (also K lo-guard: finite)
  //   kbuf  bf16[2916*256]     @ 8,128,512  live K1..K3
  //   vbufT bf16[1024*736+512] @ 9,621,504  live K1..K3 (pads zeroed by K0)
  //   obuf  bf16[324*49*256]   @ 14,745,600 live K3..K4
  //   xobuf f32 [4*3600*256]   @ 0          live K4..K5 (overlays qbuf/kbuf/vbufT)
  //   W1F @22,874,112  W2F @23,398,400  PWF @23,922,688
  //   QWF @24,053,760  KVF @24,184,832
  //   maskbuf f32[81*768]      @ 24,446,976 (ends 24,695,808)
  bf16*  qbuf  = (bf16*)(ws);
  bf16*  kbuf  = (bf16*)(ws + 8128512);
  bf16*  vbufT = (bf16*)(ws + 9621504);
  bf16*  obuf  = (bf16*)(ws + 14745600);
  float* xobuf = (float*)(ws);
  bf16*  W1F   = (bf16*)(ws + 22874112);
  bf16*  W2F   = (bf16*)(ws + 23398400);
  bf16*  PWF   = (bf16*)(ws + 23922688);
  bf16*  QWF   = (bf16*)(ws + 24053760);
  bf16*  KVF   = (bf16*)(ws + 24184832);
  float* maskbuf = (float*)(ws + 24446976);

  wt_kernel<<<3345, 256, 0, stream>>>(fc1_w, fc2_w, proj_w, q_w, kv_w,
                                      W1F, W2F, PWF, QWF, KVF, vbufT, maskbuf);
  kv_kernel<<<183, 256, 0, stream>>>(y, n1g, n1b, KVF, kbuf, vbufT);
  q_kernel<<<324, 256, 0, stream>>>(x, n1g, n1b, QWF, qbuf);
  attn_kernel<<<2592, 256, 0, stream>>>(qbuf, kbuf, vbufT, maskbuf, obuf);
  proj_kernel<<<324, 256, 0, stream>>>(obuf, x, PWF, proj_b, ls1, xobuf);
  mlp_kernel<<<900, 256, 0, stream>>>(xobuf, n2g, n2b, W1F, fc1_b, W2F, fc2_b, ls2,
                                      (float*)d_out);
}

// Round 11
// 195.392 us; speedup vs baseline: 1.1225x; 1.1225x over previous
//
#include <hip/hip_runtime.h>
#include <hip/hip_bf16.h>

typedef __hip_bfloat16 bf16;
typedef __attribute__((ext_vector_type(8))) short bf16x8;
typedef __attribute__((ext_vector_type(4))) float f32x4;

// Problem constants: B=4, H=W=60, C=256, HEADS=8, hd=32, WS=7 -> 9x9 windows/batch,
// 324 windows, 49 q/window, key window 27x27=729 gathered from the 27x27 stride-3
// grid. KEY IDENTITY: token = kk + C with C = 81*wh + 3*ww - 336 -> contiguous
// token slice; invalid keys killed by precomputed ADDITIVE mask (-30000).
// All external I/O f32; staging bf16. Softmax in log2 domain (q pre-scaled by
// hd^-0.5*log2(e); exp = v_exp_f32).
//
// Verified MFMA lane mapping (16x16x32 bf16, rounds 3-10):
//   A-frag: lane(li=lane&15, lg=lane>>4) holds A[row=li][k=lg*8+e (mod 32)]
//   B-frag: lane holds B[col=li][k=lg*8+e]
//   C/D   : [row=lg*4+r][col=li]
// Swapped QK^T: S^T = mfma(A=K, B=Q) -> lane holds S[key=t*16+lg*4+r][q=li].
// PV key<->k-slot permutation key(e)=(2c+(e>>2))*16+lg*4+(e&3) applied identically
// to the P B-frag (cvt_pk dwords) and the V A-frag reads (2x8B per frag).
// Round 11: mlp restructured to ONE fc1 pass -> whole H[16][1024] in LDS -> ONE
// fc2 pass. Barriers 9 -> 3; weight-load streams uninterrupted by vmcnt drains.

#define QSCALE 0.25505402616302864f  // (1/sqrt(32)) * log2(e)

__device__ __forceinline__ bf16 f2bf(float f){ return __float2bfloat16(f); }
__device__ __forceinline__ unsigned short f2bfu(float f){
  __hip_bfloat16 h = __float2bfloat16(f);
  return *(unsigned short*)&h;
}
__device__ __forceinline__ float fexp2(float x){
  float r; asm("v_exp_f32 %0, %1" : "=v"(r) : "v"(x)); return r;
}
__device__ __forceinline__ unsigned cvtpk(float lo, float hi){
  unsigned r; asm("v_cvt_pk_bf16_f32 %0, %1, %2" : "=v"(r) : "v"(lo), "v"(hi));
  return r;
}

// ---------------- K0: pack weights (fragment order) + vbufT pads + attn mask
__global__ __launch_bounds__(256) void wt_kernel(
    const float* __restrict__ fc1_w, const float* __restrict__ fc2_w,
    const float* __restrict__ proj_w, const float* __restrict__ q_w,
    const float* __restrict__ kv_w,
    bf16* __restrict__ W1F, bf16* __restrict__ W2F, bf16* __restrict__ PWF,
    bf16* __restrict__ QWF, bf16* __restrict__ KVF, bf16* __restrict__ vbufT,
    float* __restrict__ maskbuf){
  int gid = blockIdx.x*256 + threadIdx.x;
  if (gid < 262144){               // W1F: K=256 (kc<8), N=1024 (nt<64)
    int e=gid&7, lane=(gid>>3)&63, kc=(gid>>9)&7, nt=gid>>12;
    int li=lane&15, lg=lane>>4;
    W1F[gid] = f2bf(fc1_w[(size_t)(kc*32+lg*8+e)*1024 + nt*16+li]);
  } else if (gid < 524288){        // W2F: K=1024 (kc<32), N=256 (nt<16)
    int o = gid - 262144;
    int e=o&7, lane=(o>>3)&63, kc=(o>>9)&31, nt=o>>14;
    int li=lane&15, lg=lane>>4;
    W2F[o] = f2bf(fc2_w[(size_t)(kc*32+lg*8+e)*256 + nt*16+li]);
  } else if (gid < 589824){        // PWF: K=256 (kc<8), N=256 (nt<16)
    int o = gid - 524288;
    int e=o&7, lane=(o>>3)&63, kc=(o>>9)&7, nt=o>>12;
    int li=lane&15, lg=lane>>4;
    PWF[o] = f2bf(proj_w[(size_t)(kc*32+lg*8+e)*256 + nt*16+li]);
  } else if (gid < 655360){        // QWF: K=256, N=256, scaled by QSCALE
    int o = gid - 589824;
    int e=o&7, lane=(o>>3)&63, kc=(o>>9)&7, nt=o>>12;
    int li=lane&15, lg=lane>>4;
    QWF[o] = f2bf(q_w[(size_t)(kc*32+lg*8+e)*256 + nt*16+li] * QSCALE);
  } else if (gid < 786432){        // KVF: K=256, N=512 (nt<32)
    int o = gid - 655360;
    int e=o&7, lane=(o>>3)&63, kc=(o>>9)&7, nt=o>>12;
    int li=lane&15, lg=lane>>4;
    KVF[o] = f2bf(kv_w[(size_t)(kc*32+lg*8+e)*512 + nt*16+li]);
  } else {
    int idx = gid - 786432;
    if (idx < 7168){
      // vbufT row pads [row*736+729, +7): attn OOB V reads must be finite
      int row = idx/7, p = idx - row*7;
      vbufT[(size_t)row*736 + 729 + p] = f2bf(0.f);
    } else if (idx < 7680){
      vbufT[(size_t)1024*736 + (idx-7168)] = f2bf(0.f);  // hi-guard
    } else {
      // additive attn mask[81][768]: local key index -> 0 or -30000
      int o = idx - 7680;            // 0..62207
      int wi2 = o / 768, local = o - wi2*768;
      int wh2 = wi2/9, ww2 = wi2 - wh2*9;
      int C2 = 81*wh2 + 3*ww2 - 336;
      int off2 = C2 & 7;
      int kk = local - off2;
      bool valid = ((unsigned)kk < 729u);
      int kr = valid ? kk/27 : 0;
      int kc2 = kk - kr*27;
      int gr = wh2*3 - 12 + kr, gc = ww2*3 - 12 + kc2;
      valid = valid && ((unsigned)gr < 27u) && ((unsigned)gc < 27u)
                    && !(gr >= 24 && gc >= 24);
      maskbuf[(size_t)wi2*768 + local] = valid ? 0.f : -30000.f;
    }
  }
}

// ---------------- K1: MFMA LN(y)+kv proj -> kbuf (key-major) + vbufT (dim-major)
__global__ __launch_bounds__(256) void kv_kernel(
    const float* __restrict__ y, const float* __restrict__ g,
    const float* __restrict__ bb, const bf16* __restrict__ KVF,
    bf16* __restrict__ kbuf, bf16* __restrict__ vbufT){
  __shared__ __align__(16) unsigned short xn[16*256];  // swizzled bf16, 8 KB
  int tid = threadIdx.x, wid = tid>>6, lane = tid&63;
  int li = lane&15, lg = lane>>4;
  int tok0 = blockIdx.x * 16;
  {
    float4 g4 = ((const float4*)g)[lane];
    float4 b4 = ((const float4*)bb)[lane];
    #pragma unroll
    for (int tt=0; tt<4; tt++){
      int t = wid*4 + tt;
      int gtok = tok0 + t;
      float4 v = make_float4(0.f,0.f,0.f,0.f);
      if (gtok < 2916) v = ((const float4*)(y + (size_t)gtok*256))[lane];
      float s = v.x+v.y+v.z+v.w, ss = v.x*v.x+v.y*v.y+v.z*v.z+v.w*v.w;
      #pragma unroll
      for (int off=32; off; off>>=1){ s += __shfl_xor(s,off); ss += __shfl_xor(ss,off); }
      float mean = s*(1.f/256.f);
      float var  = fmaxf(ss*(1.f/256.f) - mean*mean, 0.f);
      float inv  = rsqrtf(var + 1e-5f);
      ushort4 pk;
      pk.x = f2bfu((v.x-mean)*inv*g4.x+b4.x);
      pk.y = f2bfu((v.y-mean)*inv*g4.y+b4.y);
      pk.z = f2bfu((v.z-mean)*inv*g4.z+b4.z);
      pk.w = f2bfu((v.w-mean)*inv*g4.w+b4.w);
      int idx = (t*256 + lane*4) ^ ((t&7)<<3);
      *(ushort4*)&xn[idx] = pk;
    }
  }
  __syncthreads();
  bf16x8 a[8];
  #pragma unroll
  for (int ks=0; ks<8; ks++){
    int idx = (li*256 + ks*32 + lg*8) ^ ((li&7)<<3);
    a[ks] = *(const bf16x8*)&xn[idx];
  }
  #pragma unroll
  for (int nn=0; nn<8; nn++){
    int ntg = wid*8 + nn;
    const bf16* wp = KVF + (size_t)ntg*4096 + lane*8;
    f32x4 acc = {0.f,0.f,0.f,0.f};
    #pragma unroll
    for (int ks=0; ks<8; ks++){
      bf16x8 bfrag = *(const bf16x8*)(wp + ks*512);
      acc = __builtin_amdgcn_mfma_f32_16x16x32_bf16(a[ks], bfrag, acc, 0, 0, 0);
    }
    int col = ntg*16 + li;
    #pragma unroll
    for (int r=0; r<4; r++){
      int tok = tok0 + lg*4 + r;
      if (tok < 2916){
        if (col < 256){
          kbuf[(size_t)tok*256 + col] = f2bf(acc[r]);
        } else {
          int b2 = (tok>=729) + (tok>=1458) + (tok>=2187);
          int ltok = tok - b2*729;
          vbufT[(size_t)(b2*256 + col-256)*736 + ltok] = f2bf(acc[r]);
        }
      }
    }
  }
}

// ---------------- K2: MFMA per-window LN(xw)+q proj (scale in QWF) ---------
__global__ __launch_bounds__(256) void q_kernel(
    const float* __restrict__ x, const float* __restrict__ g,
    const float* __restrict__ bb, const bf16* __restrict__ QWF,
    bf16* __restrict__ qbuf){
  __shared__ __align__(16) unsigned short on[64*256];  // swizzled bf16, 32 KB
  int tid = threadIdx.x, wid = tid>>6, lane = tid&63;
  int li = lane&15, lg = lane>>4;
  int w = blockIdx.x;
  int b = w/81, wi = w - b*81, wh = wi/9, ww = wi - wh*9;
  float4 g4 = ((const float4*)g)[lane];
  float4 b4 = ((const float4*)bb)[lane];
  for (int t=wid; t<64; t+=4){
    float4 v = make_float4(0.f,0.f,0.f,0.f);
    if (t < 49){
      int r = t/7, c = t - r*7;
      int gh = wh*7 + r, gw = ww*7 + c;
      if (gh < 60 && gw < 60)
        v = ((const float4*)(x + (size_t)(b*3600 + gh*60 + gw)*256))[lane];
    }
    float s=v.x+v.y+v.z+v.w, ss=v.x*v.x+v.y*v.y+v.z*v.z+v.w*v.w;
    #pragma unroll
    for (int off=32; off; off>>=1){ s += __shfl_xor(s,off); ss += __shfl_xor(ss,off); }
    float mean = s*(1.f/256.f);
    float var = fmaxf(ss*(1.f/256.f)-mean*mean, 0.f);
    float inv = rsqrtf(var+1e-5f);
    ushort4 pk;
    pk.x = f2bfu((v.x-mean)*inv*g4.x+b4.x);
    pk.y = f2bfu((v.y-mean)*inv*g4.y+b4.y);
    pk.z = f2bfu((v.z-mean)*inv*g4.z+b4.z);
    pk.w = f2bfu((v.w-mean)*inv*g4.w+b4.w);
    int idx = (t*256 + lane*4) ^ ((t&7)<<3);
    *(ushort4*)&on[idx] = pk;
  }
  __syncthreads();
  for (int rt=0; rt<4; rt++){
    bf16x8 a[8];
    #pragma unroll
    for (int ks=0; ks<8; ks++){
      int idx = ((rt*16+li)*256 + ks*32 + lg*8) ^ ((li&7)<<3);
      a[ks] = *(const bf16x8*)&on[idx];
    }
    #pragma unroll
    for (int nt=0; nt<4; nt++){
      int ntg = wid*4 + nt;
      const bf16* wp = QWF + (size_t)ntg*4096 + lane*8;
      f32x4 acc = {0.f,0.f,0.f,0.f};
      #pragma unroll
      for (int ks=0; ks<8; ks++){
        bf16x8 bfrag = *(const bf16x8*)(wp + ks*512);
        acc = __builtin_amdgcn_mfma_f32_16x16x32_bf16(a[ks], bfrag, acc, 0, 0, 0);
      }
      int col = ntg*16 + li;
      #pragma unroll
      for (int r=0; r<4; r++){
        int tok = rt*16 + lg*4 + r;
        if (tok < 49)
          qbuf[((size_t)w*49 + tok)*256 + col] = f2bf(acc[r]);
      }
    }
  }
}

// ---------------- K3: swapped-QK^T attention, LDS-staged K/V (dbuf) --------
__global__ __launch_bounds__(256) void attn_kernel(
    const bf16* __restrict__ qbuf, const bf16* __restrict__ kbuf,
    const bf16* __restrict__ vbufT, const float* __restrict__ maskbuf,
    bf16* __restrict__ obuf){
  // K fragment-order: Kls[buf][kt*512 + lane*8] (ushorts) -> ds_read_b128 lane-linear
  __shared__ __align__(16) unsigned short Kls[2][4096];   // 2 x 8 KB
  // V dim-major, row pitch 136 ushorts (17x16B): Vls[buf][d*136 + key]
  __shared__ __align__(16) unsigned short Vls[2][4352];   // 2 x 8.5 KB

  int tid = threadIdx.x, wid = tid>>6, lane = tid&63;
  int lg = lane>>4, li = lane&15;
  int blk = blockIdx.x;
  int w = blk >> 3, hh = blk & 7;
  int b = w/81, wi = w - b*81, wh = wi/9, ww = wi - wh*9;

  int C  = 81*wh + 3*ww - 336;     // token = kk + C
  int T0 = C & ~7;
  const bf16* kb = kbuf  + (long long)(b*729 + T0)*256 + hh*32;
  const bf16* vbT = vbufT + (long long)(b*256 + hh*32)*736 + T0;
  const float* mk = maskbuf + wi*768;

  // --- staging addressing (loop-invariant) ---
  const bf16* ksrcA = kb + (long long)(2*wid*16 + li)*256 + lg*8;
  const bf16* ksrcB = kb + (long long)((2*wid+1)*16 + li)*256 + lg*8;
  int vrow = tid>>4, vch = tid&15;
  const bf16* vsrcA = vbT + (long long)vrow*736 + vch*8;
  const bf16* vsrcB = vbT + (long long)(vrow+16)*736 + vch*8;

  // Q B-frag: col=q=li, k=dim lg*8+e (zero for pad rows -> s=mask only)
  bf16x8 qf;
  #pragma unroll
  for (int e=0;e<8;e++) qf[e]=0;
  int qrow = wid*16 + li;
  if (qrow < 49)
    qf = *(const bf16x8*)(qbuf + ((size_t)w*49+qrow)*256 + hh*32 + lg*8);

  f32x4 o0 = {0.f,0.f,0.f,0.f}, o1 = {0.f,0.f,0.f,0.f};  // O^T: d=lg*4+r (+16), q=li
  float m = -3.0e38f, l = 0.f;

  // --- prologue: stage tile 0 into buf 0 ---
  {
    uint4 k0 = *(const uint4*)ksrcA;
    uint4 k1 = *(const uint4*)ksrcB;
    uint4 v0 = *(const uint4*)vsrcA;
    uint4 v1 = *(const uint4*)vsrcB;
    *(uint4*)&Kls[0][2*wid*512 + lane*8]     = k0;
    *(uint4*)&Kls[0][(2*wid+1)*512 + lane*8] = k1;
    *(uint4*)&Vls[0][vrow*136 + vch*8]       = v0;
    *(uint4*)&Vls[0][(vrow+16)*136 + vch*8]  = v1;
  }
  __syncthreads();

  for (int tile=0; tile<6; tile++){
    int cur = tile & 1, nxt = cur ^ 1;
    int jbase = tile*128;
    // ---- issue next-tile global loads early (hide under compute) ----
    uint4 nk0, nk1, nv0, nv1;
    if (tile < 5){
      int jn = jbase + 128;
      nk0 = *(const uint4*)(ksrcA + (long long)jn*256);
      nk1 = *(const uint4*)(ksrcB + (long long)jn*256);
      nv0 = *(const uint4*)(vsrcA + jn);
      nv1 = *(const uint4*)(vsrcB + jn);
    }
    // ---- S^T = mfma(K, Q): s[t][r] = S[key=jbase+t*16+lg*4+r][q=li] ----
    f32x4 s[8];
    #pragma unroll
    for (int t=0;t<8;t++){
      bf16x8 kf = *(const bf16x8*)&Kls[cur][t*512 + lane*8];
      f32x4 z = {0.f,0.f,0.f,0.f};
      s[t] = __builtin_amdgcn_mfma_f32_16x16x32_bf16(kf, qf, z, 0, 0, 0);
    }
    // ---- additive mask (precomputed per window; broadcast in lg-group) ----
    #pragma unroll
    for (int t=0;t<8;t++){
      float4 mv = *(const float4*)(mk + jbase + t*16 + lg*4);
      s[t][0] += mv.x; s[t][1] += mv.y; s[t][2] += mv.z; s[t][3] += mv.w;
    }
    // ---- online softmax: lane-local 32 keys + 2 lg-group shuffles ----
    float mt = -3.0e38f;
    #pragma unroll
    for (int t=0;t<8;t++)
      mt = fmaxf(mt, fmaxf(fmaxf(s[t][0], s[t][1]), fmaxf(s[t][2], s[t][3])));
    mt = fmaxf(mt, __shfl_xor(mt, 16));
    mt = fmaxf(mt, __shfl_xor(mt, 32));
    float mn = fmaxf(m, mt);
    float fac = fexp2(m - mn);
    m = mn;
    float ps = 0.f;
    #pragma unroll
    for (int t=0;t<8;t++){
      #pragma unroll
      for (int r=0;r<4;r++){
        float p = fexp2(s[t][r] - mn);
        s[t][r] = p;
        ps += p;
      }
    }
    ps += __shfl_xor(ps, 16);
    ps += __shfl_xor(ps, 32);
    l = l*fac + ps;
    #pragma unroll
    for (int r=0;r<4;r++){ o0[r] *= fac; o1[r] *= fac; }
    // ---- P -> bf16 pairs in-register ----
    unsigned pk[8][2];
    #pragma unroll
    for (int t=0;t<8;t++){
      pk[t][0] = cvtpk(s[t][0], s[t][1]);
      pk[t][1] = cvtpk(s[t][2], s[t][3]);
    }
    // ---- O^T += mfma(A=V^T, B=P); V frags from LDS (2x8B, 2-way max) ----
    #pragma unroll
    for (int c=0;c<4;c++){
      union { unsigned u[4]; bf16x8 v; } pb, va, vc;
      pb.u[0]=pk[2*c][0];   pb.u[1]=pk[2*c][1];
      pb.u[2]=pk[2*c+1][0]; pb.u[3]=pk[2*c+1][1];
      const unsigned short* p0 = &Vls[cur][li*136 + c*32 + lg*4];
      const unsigned short* p1 = &Vls[cur][(li+16)*136 + c*32 + lg*4];
      uint2 a0 = *(const uint2*)p0, a1 = *(const uint2*)(p0+16);
      uint2 c0 = *(const uint2*)p1, c1 = *(const uint2*)(p1+16);
      va.u[0]=a0.x; va.u[1]=a0.y; va.u[2]=a1.x; va.u[3]=a1.y;
      vc.u[0]=c0.x; vc.u[1]=c0.y; vc.u[2]=c1.x; vc.u[3]=c1.y;
      o0 = __builtin_amdgcn_mfma_f32_16x16x32_bf16(va.v, pb.v, o0, 0, 0, 0);
      o1 = __builtin_amdgcn_mfma_f32_16x16x32_bf16(vc.v, pb.v, o1, 0, 0, 0);
    }
    // ---- write staged data to next buffer, then barrier ----
    if (tile < 5){
      *(uint4*)&Kls[nxt][2*wid*512 + lane*8]     = nk0;
      *(uint4*)&Kls[nxt][(2*wid+1)*512 + lane*8] = nk1;
      *(uint4*)&Vls[nxt][vrow*136 + vch*8]       = nv0;
      *(uint4*)&Vls[nxt][(vrow+16)*136 + vch*8]  = nv1;
    }
    __syncthreads();
  }

  // ---- epilogue: lane owns q=qrow, dims lg*4+r and 16+lg*4+r ----
  if (qrow < 49){
    float rl = 1.f / l;
    bf16* op = obuf + ((size_t)w*49 + qrow)*256 + hh*32;
    unsigned da0 = cvtpk(o0[0]*rl, o0[1]*rl);
    unsigned da1 = cvtpk(o0[2]*rl, o0[3]*rl);
    unsigned db0 = cvtpk(o1[0]*rl, o1[1]*rl);
    unsigned db1 = cvtpk(o1[2]*rl, o1[3]*rl);
    *(uint2*)(op + lg*4)      = make_uint2(da0, da1);
    *(uint2*)(op + 16 + lg*4) = make_uint2(db0, db1);
  }
}

// ---------------- K4: MFMA out-proj + shortcut + ls1 + window-reverse ------
__global__ __launch_bounds__(256) void proj_kernel(
    const bf16* __restrict__ obuf, const float* __restrict__ x,
    const bf16* __restrict__ PWF, const float* __restrict__ proj_b,
    const float* __restrict__ ls1, float* __restrict__ xobuf){
  __shared__ __align__(16) unsigned short on[64*256];  // swizzled bf16, 32 KB
  int tid = threadIdx.x, wid = tid>>6, lane = tid&63;
  int li = lane&15, lg = lane>>4;
  int w = blockIdx.x;
  int b = w/81, wi = w - b*81, wh = wi/9, ww = wi - wh*9;
  const bf16* ob = obuf + (size_t)w*49*256;
  for (int c=tid; c<2048; c+=256){
    int row = c>>5, col8 = (c&31)*8;
    int idx = (row*256 + col8) ^ ((row&7)<<3);
    uint4 v = make_uint4(0,0,0,0);
    if (row < 49) v = *(const uint4*)(ob + row*256 + col8);
    *(uint4*)&on[idx] = v;
  }
  float pbv[4], l1v[4];
  #pragma unroll
  for (int nt=0; nt<4; nt++){
    int col = wid*64 + nt*16 + li;
    pbv[nt] = proj_b[col];
    l1v[nt] = ls1[col];
  }
  __syncthreads();
  for (int rt=0; rt<4; rt++){
    bf16x8 a[8];
    #pragma unroll
    for (int ks=0; ks<8; ks++){
      int idx = ((rt*16+li)*256 + ks*32 + lg*8) ^ ((li&7)<<3);
      a[ks] = *(const bf16x8*)&on[idx];
    }
    #pragma unroll
    for (int nt=0; nt<4; nt++){
      int nt2 = wid*4 + nt;
      const bf16* wp = PWF + (size_t)nt2*4096 + lane*8;
      f32x4 acc = {0.f,0.f,0.f,0.f};
      #pragma unroll
      for (int ks=0; ks<8; ks++){
        bf16x8 bfrag = *(const bf16x8*)(wp + ks*512);
        acc = __builtin_amdgcn_mfma_f32_16x16x32_bf16(a[ks], bfrag, acc, 0, 0, 0);
      }
      int col = wid*64 + nt*16 + li;
      #pragma unroll
      for (int r=0; r<4; r++){
        int t = rt*16 + lg*4 + r;
        if (t < 49){
          int rr = t/7, cc = t - rr*7;
          int gh = wh*7 + rr, gw = ww*7 + cc;
          if (gh < 60 && gw < 60){
            size_t p = (size_t)(b*3600 + gh*60 + gw)*256 + col;
            xobuf[p] = x[p] + l1v[nt]*(acc[r] + pbv[nt]);
          }
        }
      }
    }
  }
}

// ---------------- K5: MFMA MLP, single-shot: LN | fc1 -> H(LDS) | fc2 ------
// 900 blocks x 16 tokens, 4 waves. Wave owns H-cols [wid*256,+256) in fc1 and
// out-cols [wid*64,+64) in fc2. H[16][1024] lives whole in LDS -> only 3
// barriers/block; each weight-load stream (128 loads) runs uninterrupted.
__global__ __launch_bounds__(256) void mlp_kernel(
    const float* __restrict__ xobuf, const float* __restrict__ g,
    const float* __restrict__ bb, const bf16* __restrict__ W1F,
    const float* __restrict__ fc1_b, const bf16* __restrict__ W2F,
    const float* __restrict__ fc2_b, const float* __restrict__ ls2,
    float* __restrict__ out){
  __shared__ __align__(16) unsigned short xn[16*256];    // swizzled bf16, 8 KB
  __shared__ __align__(16) unsigned short Hls[16*1024];  // swizzled bf16, 32 KB
  int tid = threadIdx.x, wid = tid>>6, lane = tid&63;
  int li = lane&15, lg = lane>>4;
  int tok0 = blockIdx.x * 16;
  {
    float4 g4 = ((const float4*)g)[lane];
    float4 b4 = ((const float4*)bb)[lane];
    #pragma unroll
    for (int tt=0; tt<4; tt++){
      int t = wid*4 + tt;
      float4 v = ((const float4*)(xobuf + (size_t)(tok0+t)*256))[lane];
      float s = v.x+v.y+v.z+v.w;
      float ss = v.x*v.x+v.y*v.y+v.z*v.z+v.w*v.w;
      #pragma unroll
      for (int off=32; off; off>>=1){ s += __shfl_xor(s,off); ss += __shfl_xor(ss,off); }
      float mean = s*(1.f/256.f);
      float var = fmaxf(ss*(1.f/256.f)-mean*mean, 0.f);
      float inv = rsqrtf(var+1e-5f);
      ushort4 pk;
      pk.x = f2bfu((v.x-mean)*inv*g4.x+b4.x);
      pk.y = f2bfu((v.y-mean)*inv*g4.y+b4.y);
      pk.z = f2bfu((v.z-mean)*inv*g4.z+b4.z);
      pk.w = f2bfu((v.w-mean)*inv*g4.w+b4.w);
      int idx = (t*256 + lane*4) ^ ((t&7)<<3);
      *(ushort4*)&xn[idx] = pk;
    }
  }
  __syncthreads();
  bf16x8 a1[8];
  #pragma unroll
  for (int ks=0; ks<8; ks++){
    int idx = (li*256 + ks*32 + lg*8) ^ ((li&7)<<3);
    a1[ks] = *(const bf16x8*)&xn[idx];
  }
  // ---- fc1 + GELU -> Hls: 16 col-tiles per wave, ONE uninterrupted stream ----
  #pragma unroll 4
  for (int nn=0; nn<16; nn++){
    int ntg = wid*16 + nn;                 // H col-tile (global)
    const bf16* wp = W1F + (size_t)ntg*4096 + lane*8;
    f32x4 hc = {0.f,0.f,0.f,0.f};
    #pragma unroll
    for (int ks=0; ks<8; ks++){
      bf16x8 bfrag = *(const bf16x8*)(wp + ks*512);
      hc = __builtin_amdgcn_mfma_f32_16x16x32_bf16(a1[ks], bfrag, hc, 0, 0, 0);
    }
    float bias = fc1_b[ntg*16 + li];
    int col = ntg*16 + li;                 // == LDS col (wave-disjoint slices)
    #pragma unroll
    for (int r=0; r<4; r++){
      float h = hc[r] + bias;
      float z = 0.7978845608f*(h + 0.044715f*h*h*h);   // tanh-approx GELU
      z = fminf(fmaxf(z, -15.f), 15.f);
      float e = __expf(2.f*z);
      float gv = 0.5f*h*(1.f + (e-1.f)/(e+1.f));
      int row = lg*4 + r;
      int idx = (row*1024 + col) ^ ((row&7)<<3);
      Hls[idx] = f2bfu(gv);
    }
  }
  __syncthreads();
  // ---- fc2: K=1024 in 32 chunks, ONE uninterrupted stream ----
  f32x4 oacc[4];
  #pragma unroll
  for (int nt=0; nt<4; nt++) oacc[nt] = (f32x4){0.f,0.f,0.f,0.f};
  #pragma unroll 4
  for (int kc=0; kc<32; kc++){
    int idx = (li*1024 + kc*32 + lg*8) ^ ((li&7)<<3);
    bf16x8 h0 = *(const bf16x8*)&Hls[idx];
    #pragma unroll
    for (int nt=0; nt<4; nt++){
      const bf16* wp2 = W2F + ((size_t)(wid*4+nt)*32 + kc)*512 + lane*8;
      bf16x8 bfrag = *(const bf16x8*)wp2;
      oacc[nt] = __builtin_amdgcn_mfma_f32_16x16x32_bf16(h0, bfrag, oacc[nt], 0, 0, 0);
    }
  }
  // ---- epilogue: residual + ls2 ----
  #pragma unroll
  for (int nt=0; nt<4; nt++){
    int col = wid*64 + nt*16 + li;
    float l2 = ls2[col];
    float cb = fc2_b[col];
    #pragma unroll
    for (int r=0; r<4; r++){
      int tok = tok0 + lg*4 + r;
      size_t p = (size_t)tok*256 + col;
      out[p] = xobuf[p] + l2*(oacc[nt][r] + cb);
    }
  }
}

extern "C" void kernel_launch(void* const* d_in, const int* in_sizes, int n_in,
                              void* d_out, int out_size, void* d_ws, size_t ws_size,
                              hipStream_t stream) {
  (void)in_sizes; (void)n_in; (void)out_size; (void)ws_size;
  const float* x      = (const float*)d_in[0];
  const float* y      = (const float*)d_in[1];
  const float* n1g    = (const float*)d_in[2];
  const float* n1b    = (const float*)d_in[3];
  const float* q_w    = (const float*)d_in[4];
  const float* kv_w   = (const float*)d_in[5];
  const float* proj_w = (const float*)d_in[6];
  const float* proj_b = (const float*)d_in[7];
  const float* n2g    = (const float*)d_in[8];
  const float* n2b    = (const float*)d_in[9];
  const float* fc1_w  = (const float*)d_in[10];
  const float* fc1_b  = (const float*)d_in[11];
  const float* fc2_w  = (const float*)d_in[12];
  const float* fc2_b  = (const float*)d_in[13];
  const float* ls1    = (const float*)d_in[14];
  const float* ls2    = (const float*)d_in[15];

  char* ws = (char*)d_ws;
  // Workspace (24.70 MB):
  //   qbuf  bf16[324*49*256]   @ 0          live K2..K3 (also K lo-guard: finite)
  //   kbuf  bf16[2916*256]     @ 8,128,512  live K1..K3
  //   vbufT bf16[1024*736+512] @ 9,621,504  live K1..K3 (pads zeroed by K0)
  //   obuf  bf16[324*49*256]   @ 14,745,600 live K3..K4
  //   xobuf f32 [4*3600*256]   @ 0          live K4..K5 (overlays qbuf/kbuf/vbufT)
  //   W1F @22,874,112  W2F @23,398,400  PWF @23,922,688
  //   QWF @24,053,760  KVF @24,184,832
  //   maskbuf f32[81*768]      @ 24,446,976 (ends 24,695,808)
  bf16*  qbuf  = (bf16*)(ws);
  bf16*  kbuf  = (bf16*)(ws + 8128512);
  bf16*  vbufT = (bf16*)(ws + 9621504);
  bf16*  obuf  = (bf16*)(ws + 14745600);
  float* xobuf = (float*)(ws);
  bf16*  W1F   = (bf16*)(ws + 22874112);
  bf16*  W2F   = (bf16*)(ws + 23398400);
  bf16*  PWF   = (bf16*)(ws + 23922688);
  bf16*  QWF   = (bf16*)(ws + 24053760);
  bf16*  KVF   = (bf16*)(ws + 24184832);
  float* maskbuf = (float*)(ws + 24446976);

  wt_kernel<<<3345, 256, 0, stream>>>(fc1_w, fc2_w, proj_w, q_w, kv_w,
                                      W1F, W2F, PWF, QWF, KVF, vbufT, maskbuf);
  kv_kernel<<<183, 256, 0, stream>>>(y, n1g, n1b, KVF, kbuf, vbufT);
  q_kernel<<<324, 256, 0, stream>>>(x, n1g, n1b, QWF, qbuf);
  attn_kernel<<<2592, 256, 0, stream>>>(qbuf, kbuf, vbufT, maskbuf, obuf);
  proj_kernel<<<324, 256, 0, stream>>>(obuf, x, PWF, proj_b, ls1, xobuf);
  mlp_kernel<<<900, 256, 0, stream>>>(xobuf, n2g, n2b, W1F, fc1_b, W2F, fc2_b, ls2,
                                      (float*)d_out);
}

// Round 12
// 186.405 us; speedup vs baseline: 1.1767x; 1.0482x over previous
//
#include <hip/hip_runtime.h>
#include <hip/hip_bf16.h>

typedef __hip_bfloat16 bf16;
typedef __attribute__((ext_vector_type(8))) short bf16x8;
typedef __attribute__((ext_vector_type(4))) float f32x4;

// Problem constants: B=4, H=W=60, C=256, HEADS=8, hd=32, WS=7 -> 9x9 windows/batch,
// 324 windows, 49 q/window, key window 27x27=729 gathered from the 27x27 stride-3
// grid. KEY IDENTITY: token = kk + C with C = 81*wh + 3*ww - 336 -> contiguous
// token slice; invalid keys killed by precomputed ADDITIVE mask (-30000).
// All external I/O f32; staging bf16. Softmax in log2 domain (q pre-scaled by
// hd^-0.5*log2(e); exp = v_exp_f32).
//
// Verified MFMA lane mapping (16x16x32 bf16, rounds 3-11):
//   A-frag: lane(li=lane&15, lg=lane>>4) holds A[row=li][k=lg*8+e (mod 32)]
//   B-frag: lane holds B[col=li][k=lg*8+e]
//   C/D   : [row=lg*4+r][col=li]
// Swapped QK^T: S^T = mfma(A=K, B=Q) -> lane holds S[key=t*16+lg*4+r][q=li].
// PV key<->k-slot permutation key(e)=(2c+(e>>2))*16+lg*4+(e&3) applied identically
// to the P B-frag (cvt_pk dwords) and the V A-frag layout.
// Round 12 (attn only): single-buffer LDS (16.4 KB -> ~5 blocks/CU), V staged in
// PV-FRAGMENT ORDER with XOR(c<<5) (lane-linear b128 reads; min-cycle writes),
// s_setprio(1) around the MFMA/softmax cluster.

#define QSCALE 0.25505402616302864f  // (1/sqrt(32)) * log2(e)

__device__ __forceinline__ bf16 f2bf(float f){ return __float2bfloat16(f); }
__device__ __forceinline__ unsigned short f2bfu(float f){
  __hip_bfloat16 h = __float2bfloat16(f);
  return *(unsigned short*)&h;
}
__device__ __forceinline__ float fexp2(float x){
  float r; asm("v_exp_f32 %0, %1" : "=v"(r) : "v"(x)); return r;
}
__device__ __forceinline__ unsigned cvtpk(float lo, float hi){
  unsigned r; asm("v_cvt_pk_bf16_f32 %0, %1, %2" : "=v"(r) : "v"(lo), "v"(hi));
  return r;
}

// ---------------- K0: pack weights (fragment order) + vbufT pads + attn mask
__global__ __launch_bounds__(256) void wt_kernel(
    const float* __restrict__ fc1_w, const float* __restrict__ fc2_w,
    const float* __restrict__ proj_w, const float* __restrict__ q_w,
    const float* __restrict__ kv_w,
    bf16* __restrict__ W1F, bf16* __restrict__ W2F, bf16* __restrict__ PWF,
    bf16* __restrict__ QWF, bf16* __restrict__ KVF, bf16* __restrict__ vbufT,
    float* __restrict__ maskbuf){
  int gid = blockIdx.x*256 + threadIdx.x;
  if (gid < 262144){               // W1F: K=256 (kc<8), N=1024 (nt<64)
    int e=gid&7, lane=(gid>>3)&63, kc=(gid>>9)&7, nt=gid>>12;
    int li=lane&15, lg=lane>>4;
    W1F[gid] = f2bf(fc1_w[(size_t)(kc*32+lg*8+e)*1024 + nt*16+li]);
  } else if (gid < 524288){        // W2F: K=1024 (kc<32), N=256 (nt<16)
    int o = gid - 262144;
    int e=o&7, lane=(o>>3)&63, kc=(o>>9)&31, nt=o>>14;
    int li=lane&15, lg=lane>>4;
    W2F[o] = f2bf(fc2_w[(size_t)(kc*32+lg*8+e)*256 + nt*16+li]);
  } else if (gid < 589824){        // PWF: K=256 (kc<8), N=256 (nt<16)
    int o = gid - 524288;
    int e=o&7, lane=(o>>3)&63, kc=(o>>9)&7, nt=o>>12;
    int li=lane&15, lg=lane>>4;
    PWF[o] = f2bf(proj_w[(size_t)(kc*32+lg*8+e)*256 + nt*16+li]);
  } else if (gid < 655360){        // QWF: K=256, N=256, scaled by QSCALE
    int o = gid - 589824;
    int e=o&7, lane=(o>>3)&63, kc=(o>>9)&7, nt=o>>12;
    int li=lane&15, lg=lane>>4;
    QWF[o] = f2bf(q_w[(size_t)(kc*32+lg*8+e)*256 + nt*16+li] * QSCALE);
  } else if (gid < 786432){        // KVF: K=256, N=512 (nt<32)
    int o = gid - 655360;
    int e=o&7, lane=(o>>3)&63, kc=(o>>9)&7, nt=o>>12;
    int li=lane&15, lg=lane>>4;
    KVF[o] = f2bf(kv_w[(size_t)(kc*32+lg*8+e)*512 + nt*16+li]);
  } else {
    int idx = gid - 786432;
    if (idx < 7168){
      // vbufT row pads [row*736+729, +7): attn OOB V reads must be finite
      int row = idx/7, p = idx - row*7;
      vbufT[(size_t)row*736 + 729 + p] = f2bf(0.f);
    } else if (idx < 7680){
      vbufT[(size_t)1024*736 + (idx-7168)] = f2bf(0.f);  // hi-guard
    } else {
      // additive attn mask[81][768]: local key index -> 0 or -30000
      int o = idx - 7680;            // 0..62207
      int wi2 = o / 768, local = o - wi2*768;
      int wh2 = wi2/9, ww2 = wi2 - wh2*9;
      int C2 = 81*wh2 + 3*ww2 - 336;
      int off2 = C2 & 7;
      int kk = local - off2;
      bool valid = ((unsigned)kk < 729u);
      int kr = valid ? kk/27 : 0;
      int kc2 = kk - kr*27;
      int gr = wh2*3 - 12 + kr, gc = ww2*3 - 12 + kc2;
      valid = valid && ((unsigned)gr < 27u) && ((unsigned)gc < 27u)
                    && !(gr >= 24 && gc >= 24);
      maskbuf[(size_t)wi2*768 + local] = valid ? 0.f : -30000.f;
    }
  }
}

// ---------------- K1: MFMA LN(y)+kv proj -> kbuf (key-major) + vbufT (dim-major)
__global__ __launch_bounds__(256) void kv_kernel(
    const float* __restrict__ y, const float* __restrict__ g,
    const float* __restrict__ bb, const bf16* __restrict__ KVF,
    bf16* __restrict__ kbuf, bf16* __restrict__ vbufT){
  __shared__ __align__(16) unsigned short xn[16*256];  // swizzled bf16, 8 KB
  int tid = threadIdx.x, wid = tid>>6, lane = tid&63;
  int li = lane&15, lg = lane>>4;
  int tok0 = blockIdx.x * 16;
  {
    float4 g4 = ((const float4*)g)[lane];
    float4 b4 = ((const float4*)bb)[lane];
    #pragma unroll
    for (int tt=0; tt<4; tt++){
      int t = wid*4 + tt;
      int gtok = tok0 + t;
      float4 v = make_float4(0.f,0.f,0.f,0.f);
      if (gtok < 2916) v = ((const float4*)(y + (size_t)gtok*256))[lane];
      float s = v.x+v.y+v.z+v.w, ss = v.x*v.x+v.y*v.y+v.z*v.z+v.w*v.w;
      #pragma unroll
      for (int off=32; off; off>>=1){ s += __shfl_xor(s,off); ss += __shfl_xor(ss,off); }
      float mean = s*(1.f/256.f);
      float var  = fmaxf(ss*(1.f/256.f) - mean*mean, 0.f);
      float inv  = rsqrtf(var + 1e-5f);
      ushort4 pk;
      pk.x = f2bfu((v.x-mean)*inv*g4.x+b4.x);
      pk.y = f2bfu((v.y-mean)*inv*g4.y+b4.y);
      pk.z = f2bfu((v.z-mean)*inv*g4.z+b4.z);
      pk.w = f2bfu((v.w-mean)*inv*g4.w+b4.w);
      int idx = (t*256 + lane*4) ^ ((t&7)<<3);
      *(ushort4*)&xn[idx] = pk;
    }
  }
  __syncthreads();
  bf16x8 a[8];
  #pragma unroll
  for (int ks=0; ks<8; ks++){
    int idx = (li*256 + ks*32 + lg*8) ^ ((li&7)<<3);
    a[ks] = *(const bf16x8*)&xn[idx];
  }
  #pragma unroll
  for (int nn=0; nn<8; nn++){
    int ntg = wid*8 + nn;
    const bf16* wp = KVF + (size_t)ntg*4096 + lane*8;
    f32x4 acc = {0.f,0.f,0.f,0.f};
    #pragma unroll
    for (int ks=0; ks<8; ks++){
      bf16x8 bfrag = *(const bf16x8*)(wp + ks*512);
      acc = __builtin_amdgcn_mfma_f32_16x16x32_bf16(a[ks], bfrag, acc, 0, 0, 0);
    }
    int col = ntg*16 + li;
    #pragma unroll
    for (int r=0; r<4; r++){
      int tok = tok0 + lg*4 + r;
      if (tok < 2916){
        if (col < 256){
          kbuf[(size_t)tok*256 + col] = f2bf(acc[r]);
        } else {
          int b2 = (tok>=729) + (tok>=1458) + (tok>=2187);
          int ltok = tok - b2*729;
          vbufT[(size_t)(b2*256 + col-256)*736 + ltok] = f2bf(acc[r]);
        }
      }
    }
  }
}

// ---------------- K2: MFMA per-window LN(xw)+q proj (scale in QWF) ---------
__global__ __launch_bounds__(256) void q_kernel(
    const float* __restrict__ x, const float* __restrict__ g,
    const float* __restrict__ bb, const bf16* __restrict__ QWF,
    bf16* __restrict__ qbuf){
  __shared__ __align__(16) unsigned short on[64*256];  // swizzled bf16, 32 KB
  int tid = threadIdx.x, wid = tid>>6, lane = tid&63;
  int li = lane&15, lg = lane>>4;
  int w = blockIdx.x;
  int b = w/81, wi = w - b*81, wh = wi/9, ww = wi - wh*9;
  float4 g4 = ((const float4*)g)[lane];
  float4 b4 = ((const float4*)bb)[lane];
  for (int t=wid; t<64; t+=4){
    float4 v = make_float4(0.f,0.f,0.f,0.f);
    if (t < 49){
      int r = t/7, c = t - r*7;
      int gh = wh*7 + r, gw = ww*7 + c;
      if (gh < 60 && gw < 60)
        v = ((const float4*)(x + (size_t)(b*3600 + gh*60 + gw)*256))[lane];
    }
    float s=v.x+v.y+v.z+v.w, ss=v.x*v.x+v.y*v.y+v.z*v.z+v.w*v.w;
    #pragma unroll
    for (int off=32; off; off>>=1){ s += __shfl_xor(s,off); ss += __shfl_xor(ss,off); }
    float mean = s*(1.f/256.f);
    float var = fmaxf(ss*(1.f/256.f)-mean*mean, 0.f);
    float inv = rsqrtf(var+1e-5f);
    ushort4 pk;
    pk.x = f2bfu((v.x-mean)*inv*g4.x+b4.x);
    pk.y = f2bfu((v.y-mean)*inv*g4.y+b4.y);
    pk.z = f2bfu((v.z-mean)*inv*g4.z+b4.z);
    pk.w = f2bfu((v.w-mean)*inv*g4.w+b4.w);
    int idx = (t*256 + lane*4) ^ ((t&7)<<3);
    *(ushort4*)&on[idx] = pk;
  }
  __syncthreads();
  for (int rt=0; rt<4; rt++){
    bf16x8 a[8];
    #pragma unroll
    for (int ks=0; ks<8; ks++){
      int idx = ((rt*16+li)*256 + ks*32 + lg*8) ^ ((li&7)<<3);
      a[ks] = *(const bf16x8*)&on[idx];
    }
    #pragma unroll
    for (int nt=0; nt<4; nt++){
      int ntg = wid*4 + nt;
      const bf16* wp = QWF + (size_t)ntg*4096 + lane*8;
      f32x4 acc = {0.f,0.f,0.f,0.f};
      #pragma unroll
      for (int ks=0; ks<8; ks++){
        bf16x8 bfrag = *(const bf16x8*)(wp + ks*512);
        acc = __builtin_amdgcn_mfma_f32_16x16x32_bf16(a[ks], bfrag, acc, 0, 0, 0);
      }
      int col = ntg*16 + li;
      #pragma unroll
      for (int r=0; r<4; r++){
        int tok = rt*16 + lg*4 + r;
        if (tok < 49)
          qbuf[((size_t)w*49 + tok)*256 + col] = f2bf(acc[r]);
      }
    }
  }
}

// ---------------- K3: swapped-QK^T attention, single-buffer frag-order LDS -
// block = (window, head), 4 waves x 16 q-slots. 16.4 KB LDS -> ~5 blocks/CU.
// Per tile: issue next loads -> compute (setprio-boosted) -> barrier -> ds_write
// -> barrier. V stored in PV-fragment order with XOR(c<<5) bank spreading.
__global__ __launch_bounds__(256) void attn_kernel(
    const bf16* __restrict__ qbuf, const bf16* __restrict__ kbuf,
    const bf16* __restrict__ vbufT, const float* __restrict__ maskbuf,
    bf16* __restrict__ obuf){
  __shared__ __align__(16) unsigned short Kls[4096];   // frag-order K, 8 KB
  __shared__ __align__(16) unsigned short VlsF[8192];  // frag-order V, 2x4 KB regions

  int tid = threadIdx.x, wid = tid>>6, lane = tid&63;
  int lg = lane>>4, li = lane&15;
  int blk = blockIdx.x;
  int w = blk >> 3, hh = blk & 7;
  int b = w/81, wi = w - b*81, wh = wi/9, ww = wi - wh*9;

  int C  = 81*wh + 3*ww - 336;     // token = kk + C
  int T0 = C & ~7;
  const bf16* kb  = kbuf  + (long long)(b*729 + T0)*256 + hh*32;
  const bf16* vbT = vbufT + (long long)(b*256 + hh*32)*736 + T0;
  const float* mk = maskbuf + wi*768;

  // --- staging addressing (loop-invariant) ---
  // K: wave wid stages kt = 2*wid, 2*wid+1; lane stages its own frag slot.
  const bf16* ksrcA = kb + (long long)(2*wid*16 + li)*256 + lg*8;
  const bf16* ksrcB = kb + (long long)((2*wid+1)*16 + li)*256 + lg*8;
  // V: thread -> row d = tid>>4 (and d+16), key-chunk vch = tid&15 (8 keys).
  int vrow = tid>>4, vch = tid&15;
  const bf16* vsrcA = vbT + (long long)vrow*736 + vch*8;
  const bf16* vsrcB = vbT + (long long)(vrow+16)*736 + vch*8;
  // V frag-order write targets: key group c=vch>>2, half=(vch>>1)&1, lg0=(vch&1)*2
  int vc_ = vch>>2, vhalf = (vch>>1)&1, vlg0 = (vch&1)*2;
  unsigned vdst0 = (unsigned)(((vc_*64 + vlg0*16     + vrow)*16 + vhalf*8) ^ (vc_<<5));
  unsigned vdst1 = (unsigned)(((vc_*64 + (vlg0+1)*16 + vrow)*16 + vhalf*8) ^ (vc_<<5));

  // Q B-frag: col=q=li, k=dim lg*8+e (zero for pad rows -> s=mask only)
  bf16x8 qf;
  #pragma unroll
  for (int e=0;e<8;e++) qf[e]=0;
  int qrow = wid*16 + li;
  if (qrow < 49)
    qf = *(const bf16x8*)(qbuf + ((size_t)w*49+qrow)*256 + hh*32 + lg*8);

  f32x4 o0 = {0.f,0.f,0.f,0.f}, o1 = {0.f,0.f,0.f,0.f};  // O^T: d=lg*4+r (+16), q=li
  float m = -3.0e38f, l = 0.f;

  // --- prologue: stage tile 0 ---
  {
    uint4 k0 = *(const uint4*)ksrcA;
    uint4 k1 = *(const uint4*)ksrcB;
    uint4 v0 = *(const uint4*)vsrcA;
    uint4 v1 = *(const uint4*)vsrcB;
    *(uint4*)&Kls[2*wid*512 + lane*8]     = k0;
    *(uint4*)&Kls[(2*wid+1)*512 + lane*8] = k1;
    *(uint2*)((char*)VlsF + vdst0)        = make_uint2(v0.x, v0.y);
    *(uint2*)((char*)VlsF + vdst1)        = make_uint2(v0.z, v0.w);
    *(uint2*)((char*)VlsF + 8192 + vdst0) = make_uint2(v1.x, v1.y);
    *(uint2*)((char*)VlsF + 8192 + vdst1) = make_uint2(v1.z, v1.w);
  }
  __syncthreads();

  for (int tile=0; tile<6; tile++){
    int jbase = tile*128;
    // ---- issue next-tile global loads early (hide under compute) ----
    uint4 nk0, nk1, nv0, nv1;
    if (tile < 5){
      int jn = jbase + 128;
      nk0 = *(const uint4*)(ksrcA + (long long)jn*256);
      nk1 = *(const uint4*)(ksrcB + (long long)jn*256);
      nv0 = *(const uint4*)(vsrcA + jn);
      nv1 = *(const uint4*)(vsrcB + jn);
    }
    __builtin_amdgcn_s_setprio(1);
    // ---- S^T = mfma(K, Q): s[t][r] = S[key=jbase+t*16+lg*4+r][q=li] ----
    f32x4 s[8];
    #pragma unroll
    for (int t=0;t<8;t++){
      bf16x8 kf = *(const bf16x8*)&Kls[t*512 + lane*8];
      f32x4 z = {0.f,0.f,0.f,0.f};
      s[t] = __builtin_amdgcn_mfma_f32_16x16x32_bf16(kf, qf, z, 0, 0, 0);
    }
    // ---- additive mask (precomputed per window; broadcast in lg-group) ----
    #pragma unroll
    for (int t=0;t<8;t++){
      float4 mv = *(const float4*)(mk + jbase + t*16 + lg*4);
      s[t][0] += mv.x; s[t][1] += mv.y; s[t][2] += mv.z; s[t][3] += mv.w;
    }
    // ---- online softmax: lane-local 32 keys + 2 lg-group shuffles ----
    float mt = -3.0e38f;
    #pragma unroll
    for (int t=0;t<8;t++)
      mt = fmaxf(mt, fmaxf(fmaxf(s[t][0], s[t][1]), fmaxf(s[t][2], s[t][3])));
    mt = fmaxf(mt, __shfl_xor(mt, 16));
    mt = fmaxf(mt, __shfl_xor(mt, 32));
    float mn = fmaxf(m, mt);
    float fac = fexp2(m - mn);
    m = mn;
    float ps = 0.f;
    #pragma unroll
    for (int t=0;t<8;t++){
      #pragma unroll
      for (int r=0;r<4;r++){
        float p = fexp2(s[t][r] - mn);
        s[t][r] = p;
        ps += p;
      }
    }
    ps += __shfl_xor(ps, 16);
    ps += __shfl_xor(ps, 32);
    l = l*fac + ps;
    #pragma unroll
    for (int r=0;r<4;r++){ o0[r] *= fac; o1[r] *= fac; }
    // ---- P -> bf16 pairs in-register ----
    unsigned pk[8][2];
    #pragma unroll
    for (int t=0;t<8;t++){
      pk[t][0] = cvtpk(s[t][0], s[t][1]);
      pk[t][1] = cvtpk(s[t][2], s[t][3]);
    }
    // ---- O^T += mfma(A=V^T, B=P); V frags: one b128 each, lane-linear ----
    #pragma unroll
    for (int c=0;c<4;c++){
      union { unsigned u[4]; bf16x8 v; } pb;
      pb.u[0]=pk[2*c][0];   pb.u[1]=pk[2*c][1];
      pb.u[2]=pk[2*c+1][0]; pb.u[3]=pk[2*c+1][1];
      unsigned off = (unsigned)(((c*64 + lg*16 + li)*16) ^ (c<<5));
      bf16x8 va = *(const bf16x8*)((const char*)VlsF + off);
      bf16x8 vcf = *(const bf16x8*)((const char*)VlsF + 8192 + off);
      o0 = __builtin_amdgcn_mfma_f32_16x16x32_bf16(va,  pb.v, o0, 0, 0, 0);
      o1 = __builtin_amdgcn_mfma_f32_16x16x32_bf16(vcf, pb.v, o1, 0, 0, 0);
    }
    __builtin_amdgcn_s_setprio(0);
    // ---- single buffer: drain reads, then overwrite with next tile ----
    if (tile < 5){
      __syncthreads();
      *(uint4*)&Kls[2*wid*512 + lane*8]     = nk0;
      *(uint4*)&Kls[(2*wid+1)*512 + lane*8] = nk1;
      *(uint2*)((char*)VlsF + vdst0)        = make_uint2(nv0.x, nv0.y);
      *(uint2*)((char*)VlsF + vdst1)        = make_uint2(nv0.z, nv0.w);
      *(uint2*)((char*)VlsF + 8192 + vdst0) = make_uint2(nv1.x, nv1.y);
      *(uint2*)((char*)VlsF + 8192 + vdst1) = make_uint2(nv1.z, nv1.w);
      __syncthreads();
    }
  }

  // ---- epilogue: lane owns q=qrow, dims lg*4+r and 16+lg*4+r ----
  if (qrow < 49){
    float rl = 1.f / l;
    bf16* op = obuf + ((size_t)w*49 + qrow)*256 + hh*32;
    unsigned da0 = cvtpk(o0[0]*rl, o0[1]*rl);
    unsigned da1 = cvtpk(o0[2]*rl, o0[3]*rl);
    unsigned db0 = cvtpk(o1[0]*rl, o1[1]*rl);
    unsigned db1 = cvtpk(o1[2]*rl, o1[3]*rl);
    *(uint2*)(op + lg*4)      = make_uint2(da0, da1);
    *(uint2*)(op + 16 + lg*4) = make_uint2(db0, db1);
  }
}

// ---------------- K4: MFMA out-proj + shortcut + ls1 + window-reverse ------
__global__ __launch_bounds__(256) void proj_kernel(
    const bf16* __restrict__ obuf, const float* __restrict__ x,
    const bf16* __restrict__ PWF, const float* __restrict__ proj_b,
    const float* __restrict__ ls1, float* __restrict__ xobuf){
  __shared__ __align__(16) unsigned short on[64*256];  // swizzled bf16, 32 KB
  int tid = threadIdx.x, wid = tid>>6, lane = tid&63;
  int li = lane&15, lg = lane>>4;
  int w = blockIdx.x;
  int b = w/81, wi = w - b*81, wh = wi/9, ww = wi - wh*9;
  const bf16* ob = obuf + (size_t)w*49*256;
  for (int c=tid; c<2048; c+=256){
    int row = c>>5, col8 = (c&31)*8;
    int idx = (row*256 + col8) ^ ((row&7)<<3);
    uint4 v = make_uint4(0,0,0,0);
    if (row < 49) v = *(const uint4*)(ob + row*256 + col8);
    *(uint4*)&on[idx] = v;
  }
  float pbv[4], l1v[4];
  #pragma unroll
  for (int nt=0; nt<4; nt++){
    int col = wid*64 + nt*16 + li;
    pbv[nt] = proj_b[col];
    l1v[nt] = ls1[col];
  }
  __syncthreads();
  for (int rt=0; rt<4; rt++){
    bf16x8 a[8];
    #pragma unroll
    for (int ks=0; ks<8; ks++){
      int idx = ((rt*16+li)*256 + ks*32 + lg*8) ^ ((li&7)<<3);
      a[ks] = *(const bf16x8*)&on[idx];
    }
    #pragma unroll
    for (int nt=0; nt<4; nt++){
      int nt2 = wid*4 + nt;
      const bf16* wp = PWF + (size_t)nt2*4096 + lane*8;
      f32x4 acc = {0.f,0.f,0.f,0.f};
      #pragma unroll
      for (int ks=0; ks<8; ks++){
        bf16x8 bfrag = *(const bf16x8*)(wp + ks*512);
        acc = __builtin_amdgcn_mfma_f32_16x16x32_bf16(a[ks], bfrag, acc, 0, 0, 0);
      }
      int col = wid*64 + nt*16 + li;
      #pragma unroll
      for (int r=0; r<4; r++){
        int t = rt*16 + lg*4 + r;
        if (t < 49){
          int rr = t/7, cc = t - rr*7;
          int gh = wh*7 + rr, gw = ww*7 + cc;
          if (gh < 60 && gw < 60){
            size_t p = (size_t)(b*3600 + gh*60 + gw)*256 + col;
            xobuf[p] = x[p] + l1v[nt]*(acc[r] + pbv[nt]);
          }
        }
      }
    }
  }
}

// ---------------- K5: MFMA MLP, single-shot: LN | fc1 -> H(LDS) | fc2 ------
__global__ __launch_bounds__(256) void mlp_kernel(
    const float* __restrict__ xobuf, const float* __restrict__ g,
    const float* __restrict__ bb, const bf16* __restrict__ W1F,
    const float* __restrict__ fc1_b, const bf16* __restrict__ W2F,
    const float* __restrict__ fc2_b, const float* __restrict__ ls2,
    float* __restrict__ out){
  __shared__ __align__(16) unsigned short xn[16*256];    // swizzled bf16, 8 KB
  __shared__ __align__(16) unsigned short Hls[16*1024];  // swizzled bf16, 32 KB
  int tid = threadIdx.x, wid = tid>>6, lane = tid&63;
  int li = lane&15, lg = lane>>4;
  int tok0 = blockIdx.x * 16;
  {
    float4 g4 = ((const float4*)g)[lane];
    float4 b4 = ((const float4*)bb)[lane];
    #pragma unroll
    for (int tt=0; tt<4; tt++){
      int t = wid*4 + tt;
      float4 v = ((const float4*)(xobuf + (size_t)(tok0+t)*256))[lane];
      float s = v.x+v.y+v.z+v.w;
      float ss = v.x*v.x+v.y*v.y+v.z*v.z+v.w*v.w;
      #pragma unroll
      for (int off=32; off; off>>=1){ s += __shfl_xor(s,off); ss += __shfl_xor(ss,off); }
      float mean = s*(1.f/256.f);
      float var = fmaxf(ss*(1.f/256.f)-mean*mean, 0.f);
      float inv = rsqrtf(var+1e-5f);
      ushort4 pk;
      pk.x = f2bfu((v.x-mean)*inv*g4.x+b4.x);
      pk.y = f2bfu((v.y-mean)*inv*g4.y+b4.y);
      pk.z = f2bfu((v.z-mean)*inv*g4.z+b4.z);
      pk.w = f2bfu((v.w-mean)*inv*g4.w+b4.w);
      int idx = (t*256 + lane*4) ^ ((t&7)<<3);
      *(ushort4*)&xn[idx] = pk;
    }
  }
  __syncthreads();
  bf16x8 a1[8];
  #pragma unroll
  for (int ks=0; ks<8; ks++){
    int idx = (li*256 + ks*32 + lg*8) ^ ((li&7)<<3);
    a1[ks] = *(const bf16x8*)&xn[idx];
  }
  // ---- fc1 + GELU -> Hls: 16 col-tiles per wave, ONE uninterrupted stream ----
  #pragma unroll 4
  for (int nn=0; nn<16; nn++){
    int ntg = wid*16 + nn;                 // H col-tile (global)
    const bf16* wp = W1F + (size_t)ntg*4096 + lane*8;
    f32x4 hc = {0.f,0.f,0.f,0.f};
    #pragma unroll
    for (int ks=0; ks<8; ks++){
      bf16x8 bfrag = *(const bf16x8*)(wp + ks*512);
      hc = __builtin_amdgcn_mfma_f32_16x16x32_bf16(a1[ks], bfrag, hc, 0, 0, 0);
    }
    float bias = fc1_b[ntg*16 + li];
    int col = ntg*16 + li;                 // == LDS col (wave-disjoint slices)
    #pragma unroll
    for (int r=0; r<4; r++){
      float h = hc[r] + bias;
      float z = 0.7978845608f*(h + 0.044715f*h*h*h);   // tanh-approx GELU
      z = fminf(fmaxf(z, -15.f), 15.f);
      float e = __expf(2.f*z);
      float gv = 0.5f*h*(1.f + (e-1.f)/(e+1.f));
      int row = lg*4 + r;
      int idx = (row*1024 + col) ^ ((row&7)<<3);
      Hls[idx] = f2bfu(gv);
    }
  }
  __syncthreads();
  // ---- fc2: K=1024 in 32 chunks, ONE uninterrupted stream ----
  f32x4 oacc[4];
  #pragma unroll
  for (int nt=0; nt<4; nt++) oacc[nt] = (f32x4){0.f,0.f,0.f,0.f};
  #pragma unroll 4
  for (int kc=0; kc<32; kc++){
    int idx = (li*1024 + kc*32 + lg*8) ^ ((li&7)<<3);
    bf16x8 h0 = *(const bf16x8*)&Hls[idx];
    #pragma unroll
    for (int nt=0; nt<4; nt++){
      const bf16* wp2 = W2F + ((size_t)(wid*4+nt)*32 + kc)*512 + lane*8;
      bf16x8 bfrag = *(const bf16x8*)wp2;
      oacc[nt] = __builtin_amdgcn_mfma_f32_16x16x32_bf16(h0, bfrag, oacc[nt], 0, 0, 0);
    }
  }
  // ---- epilogue: residual + ls2 ----
  #pragma unroll
  for (int nt=0; nt<4; nt++){
    int col = wid*64 + nt*16 + li;
    float l2 = ls2[col];
    float cb = fc2_b[col];
    #pragma unroll
    for (int r=0; r<4; r++){
      int tok = tok0 + lg*4 + r;
      size_t p = (size_t)tok*256 + col;
      out[p] = xobuf[p] + l2*(oacc[nt][r] + cb);
    }
  }
}

extern "C" void kernel_launch(void* const* d_in, const int* in_sizes, int n_in,
                              void* d_out, int out_size, void* d_ws, size_t ws_size,
                              hipStream_t stream) {
  (void)in_sizes; (void)n_in; (void)out_size; (void)ws_size;
  const float* x      = (const float*)d_in[0];
  const float* y      = (const float*)d_in[1];
  const float* n1g    = (const float*)d_in[2];
  const float* n1b    = (const float*)d_in[3];
  const float* q_w    = (const float*)d_in[4];
  const float* kv_w   = (const float*)d_in[5];
  const float* proj_w = (const float*)d_in[6];
  const float* proj_b = (const float*)d_in[7];
  const float* n2g    = (const float*)d_in[8];
  const float* n2b    = (const float*)d_in[9];
  const float* fc1_w  = (const float*)d_in[10];
  const float* fc1_b  = (const float*)d_in[11];
  const float* fc2_w  = (const float*)d_in[12];
  const float* fc2_b  = (const float*)d_in[13];
  const float* ls1    = (const float*)d_in[14];
  const float* ls2    = (const float*)d_in[15];

  char* ws = (char*)d_ws;
  // Workspace (24.70 MB):
  //   qbuf  bf16[324*49*256]   @ 0          live K2..K3 (also K lo-guard: finite)
  //   kbuf  bf16[2916*256]     @ 8,128,512  live K1..K3
  //   vbufT bf16[1024*736+512] @ 9,621,504  live K1..K3 (pads zeroed by K0)
  //   obuf  bf16[324*49*256]   @ 14,745,600 live K3..K4
  //   xobuf f32 [4*3600*256]   @ 0          live K4..K5 (overlays qbuf/kbuf/vbufT)
  //   W1F @22,874,112  W2F @23,398,400  PWF @23,922,688
  //   QWF @24,053,760  KVF @24,184,832
  //   maskbuf f32[81*768]      @ 24,446,976 (ends 24,695,808)
  bf16*  qbuf  = (bf16*)(ws);
  bf16*  kbuf  = (bf16*)(ws + 8128512);
  bf16*  vbufT = (bf16*)(ws + 9621504);
  bf16*  obuf  = (bf16*)(ws + 14745600);
  float* xobuf = (float*)(ws);
  bf16*  W1F   = (bf16*)(ws + 22874112);
  bf16*  W2F   = (bf16*)(ws + 23398400);
  bf16*  PWF   = (bf16*)(ws + 23922688);
  bf16*  QWF   = (bf16*)(ws + 24053760);
  bf16*  KVF   = (bf16*)(ws + 24184832);
  float* maskbuf = (float*)(ws + 24446976);

  wt_kernel<<<3345, 256, 0, stream>>>(fc1_w, fc2_w, proj_w, q_w, kv_w,
                                      W1F, W2F, PWF, QWF, KVF, vbufT, maskbuf);
  kv_kernel<<<183, 256, 0, stream>>>(y, n1g, n1b, KVF, kbuf, vbufT);
  q_kernel<<<324, 256, 0, stream>>>(x, n1g, n1b, QWF, qbuf);
  attn_kernel<<<2592, 256, 0, stream>>>(qbuf, kbuf, vbufT, maskbuf, obuf);
  proj_kernel<<<324, 256, 0, stream>>>(obuf, x, PWF, proj_b, ls1, xobuf);
  mlp_kernel<<<900, 256, 0, stream>>>(xobuf, n2g, n2b, W1F, fc1_b, W2F, fc2_b, ls2,
                                      (float*)d_out);
}

// Round 13
// 144.532 us; speedup vs baseline: 1.5176x; 1.2897x over previous
//
#include <hip/hip_runtime.h>
#include <hip/hip_bf16.h>

typedef __hip_bfloat16 bf16;
typedef __attribute__((ext_vector_type(8))) short bf16x8;
typedef __attribute__((ext_vector_type(4))) float f32x4;

// Problem constants: B=4, H=W=60, C=256, HEADS=8, hd=32, WS=7 -> 9x9 windows/batch,
// 324 windows, 49 q/window, key window 27x27=729 gathered from the 27x27 stride-3
// grid. KEY IDENTITY: token = kk + C with C = 81*wh + 3*ww - 336 -> contiguous
// token slice; invalid keys killed by precomputed ADDITIVE mask (-30000).
// All external I/O f32; staging bf16. Softmax in log2 domain (q pre-scaled by
// hd^-0.5*log2(e); exp = v_exp_f32).
//
// Verified MFMA lane mapping (16x16x32 bf16, rounds 3-12):
//   A-frag: lane(li=lane&15, lg=lane>>4) holds A[row=li][k=lg*8+e (mod 32)]
//   B-frag: lane holds B[col=li][k=lg*8+e]
//   C/D   : [row=lg*4+r][col=li]
// Swapped QK^T: S^T = mfma(A=K, B=Q) -> lane holds S[key=t*16+lg*4+r][q=li].
// PV key<->k-slot permutation key(e)=(2c+(e>>2))*16+lg*4+(e&3) applied identically
// to the P B-frag (cvt_pk dwords) and the V A-frag layout.
// Round 13: q/proj re-gridded as per-token GEMMs (993 blocks, was 324 = 1.27/CU);
// proj has ZERO LDS / barriers (direct per-lane A loads from row-linear obuf);
// mlp gets explicit 1-iter register double-buffering of weight B-frags.

#define QSCALE 0.25505402616302864f  // (1/sqrt(32)) * log2(e)

__device__ __forceinline__ bf16 f2bf(float f){ return __float2bfloat16(f); }
__device__ __forceinline__ unsigned short f2bfu(float f){
  __hip_bfloat16 h = __float2bfloat16(f);
  return *(unsigned short*)&h;
}
__device__ __forceinline__ float fexp2(float x){
  float r; asm("v_exp_f32 %0, %1" : "=v"(r) : "v"(x)); return r;
}
__device__ __forceinline__ unsigned cvtpk(float lo, float hi){
  unsigned r; asm("v_cvt_pk_bf16_f32 %0, %1, %2" : "=v"(r) : "v"(lo), "v"(hi));
  return r;
}

// ---------------- K0: pack weights (fragment order) + vbufT pads + attn mask
__global__ __launch_bounds__(256) void wt_kernel(
    const float* __restrict__ fc1_w, const float* __restrict__ fc2_w,
    const float* __restrict__ proj_w, const float* __restrict__ q_w,
    const float* __restrict__ kv_w,
    bf16* __restrict__ W1F, bf16* __restrict__ W2F, bf16* __restrict__ PWF,
    bf16* __restrict__ QWF, bf16* __restrict__ KVF, bf16* __restrict__ vbufT,
    float* __restrict__ maskbuf){
  int gid = blockIdx.x*256 + threadIdx.x;
  if (gid < 262144){               // W1F: K=256 (kc<8), N=1024 (nt<64)
    int e=gid&7, lane=(gid>>3)&63, kc=(gid>>9)&7, nt=gid>>12;
    int li=lane&15, lg=lane>>4;
    W1F[gid] = f2bf(fc1_w[(size_t)(kc*32+lg*8+e)*1024 + nt*16+li]);
  } else if (gid < 524288){        // W2F: K=1024 (kc<32), N=256 (nt<16)
    int o = gid - 262144;
    int e=o&7, lane=(o>>3)&63, kc=(o>>9)&31, nt=o>>14;
    int li=lane&15, lg=lane>>4;
    W2F[o] = f2bf(fc2_w[(size_t)(kc*32+lg*8+e)*256 + nt*16+li]);
  } else if (gid < 589824){        // PWF: K=256 (kc<8), N=256 (nt<16)
    int o = gid - 524288;
    int e=o&7, lane=(o>>3)&63, kc=(o>>9)&7, nt=o>>12;
    int li=lane&15, lg=lane>>4;
    PWF[o] = f2bf(proj_w[(size_t)(kc*32+lg*8+e)*256 + nt*16+li]);
  } else if (gid < 655360){        // QWF: K=256, N=256, scaled by QSCALE
    int o = gid - 589824;
    int e=o&7, lane=(o>>3)&63, kc=(o>>9)&7, nt=o>>12;
    int li=lane&15, lg=lane>>4;
    QWF[o] = f2bf(q_w[(size_t)(kc*32+lg*8+e)*256 + nt*16+li] * QSCALE);
  } else if (gid < 786432){        // KVF: K=256, N=512 (nt<32)
    int o = gid - 655360;
    int e=o&7, lane=(o>>3)&63, kc=(o>>9)&7, nt=o>>12;
    int li=lane&15, lg=lane>>4;
    KVF[o] = f2bf(kv_w[(size_t)(kc*32+lg*8+e)*512 + nt*16+li]);
  } else {
    int idx = gid - 786432;
    if (idx < 7168){
      // vbufT row pads [row*736+729, +7): attn OOB V reads must be finite
      int row = idx/7, p = idx - row*7;
      vbufT[(size_t)row*736 + 729 + p] = f2bf(0.f);
    } else if (idx < 7680){
      vbufT[(size_t)1024*736 + (idx-7168)] = f2bf(0.f);  // hi-guard
    } else {
      // additive attn mask[81][768]: local key index -> 0 or -30000
      int o = idx - 7680;            // 0..62207
      int wi2 = o / 768, local = o - wi2*768;
      int wh2 = wi2/9, ww2 = wi2 - wh2*9;
      int C2 = 81*wh2 + 3*ww2 - 336;
      int off2 = C2 & 7;
      int kk = local - off2;
      bool valid = ((unsigned)kk < 729u);
      int kr = valid ? kk/27 : 0;
      int kc2 = kk - kr*27;
      int gr = wh2*3 - 12 + kr, gc = ww2*3 - 12 + kc2;
      valid = valid && ((unsigned)gr < 27u) && ((unsigned)gc < 27u)
                    && !(gr >= 24 && gc >= 24);
      maskbuf[(size_t)wi2*768 + local] = valid ? 0.f : -30000.f;
    }
  }
}

// ---------------- K1: MFMA LN(y)+kv proj -> kbuf (key-major) + vbufT (dim-major)
__global__ __launch_bounds__(256) void kv_kernel(
    const float* __restrict__ y, const float* __restrict__ g,
    const float* __restrict__ bb, const bf16* __restrict__ KVF,
    bf16* __restrict__ kbuf, bf16* __restrict__ vbufT){
  __shared__ __align__(16) unsigned short xn[16*256];  // swizzled bf16, 8 KB
  int tid = threadIdx.x, wid = tid>>6, lane = tid&63;
  int li = lane&15, lg = lane>>4;
  int tok0 = blockIdx.x * 16;
  {
    float4 g4 = ((const float4*)g)[lane];
    float4 b4 = ((const float4*)bb)[lane];
    #pragma unroll
    for (int tt=0; tt<4; tt++){
      int t = wid*4 + tt;
      int gtok = tok0 + t;
      float4 v = make_float4(0.f,0.f,0.f,0.f);
      if (gtok < 2916) v = ((const float4*)(y + (size_t)gtok*256))[lane];
      float s = v.x+v.y+v.z+v.w, ss = v.x*v.x+v.y*v.y+v.z*v.z+v.w*v.w;
      #pragma unroll
      for (int off=32; off; off>>=1){ s += __shfl_xor(s,off); ss += __shfl_xor(ss,off); }
      float mean = s*(1.f/256.f);
      float var  = fmaxf(ss*(1.f/256.f) - mean*mean, 0.f);
      float inv  = rsqrtf(var + 1e-5f);
      ushort4 pk;
      pk.x = f2bfu((v.x-mean)*inv*g4.x+b4.x);
      pk.y = f2bfu((v.y-mean)*inv*g4.y+b4.y);
      pk.z = f2bfu((v.z-mean)*inv*g4.z+b4.z);
      pk.w = f2bfu((v.w-mean)*inv*g4.w+b4.w);
      int idx = (t*256 + lane*4) ^ ((t&7)<<3);
      *(ushort4*)&xn[idx] = pk;
    }
  }
  __syncthreads();
  bf16x8 a[8];
  #pragma unroll
  for (int ks=0; ks<8; ks++){
    int idx = (li*256 + ks*32 + lg*8) ^ ((li&7)<<3);
    a[ks] = *(const bf16x8*)&xn[idx];
  }
  #pragma unroll
  for (int nn=0; nn<8; nn++){
    int ntg = wid*8 + nn;
    const bf16* wp = KVF + (size_t)ntg*4096 + lane*8;
    f32x4 acc = {0.f,0.f,0.f,0.f};
    #pragma unroll
    for (int ks=0; ks<8; ks++){
      bf16x8 bfrag = *(const bf16x8*)(wp + ks*512);
      acc = __builtin_amdgcn_mfma_f32_16x16x32_bf16(a[ks], bfrag, acc, 0, 0, 0);
    }
    int col = ntg*16 + li;
    #pragma unroll
    for (int r=0; r<4; r++){
      int tok = tok0 + lg*4 + r;
      if (tok < 2916){
        if (col < 256){
          kbuf[(size_t)tok*256 + col] = f2bf(acc[r]);
        } else {
          int b2 = (tok>=729) + (tok>=1458) + (tok>=2187);
          int ltok = tok - b2*729;
          vbufT[(size_t)(b2*256 + col-256)*736 + ltok] = f2bf(acc[r]);
        }
      }
    }
  }
}

// ---------------- K2: per-token MFMA LN(x)+q proj (993 blocks x 16 rows) ----
// row = w*49 + t (window-row). Pad rows (gh/gw >= 60 or row >= 15876) get
// LN(0) = bias values -> qbuf stays fully written (attn reads all t<49).
__global__ __launch_bounds__(256) void q_kernel(
    const float* __restrict__ x, const float* __restrict__ g,
    const float* __restrict__ bb, const bf16* __restrict__ QWF,
    bf16* __restrict__ qbuf){
  __shared__ __align__(16) unsigned short xn[16*256];  // swizzled bf16, 8 KB
  int tid = threadIdx.x, wid = tid>>6, lane = tid&63;
  int li = lane&15, lg = lane>>4;
  int row0 = blockIdx.x * 16;
  {
    float4 g4 = ((const float4*)g)[lane];
    float4 b4 = ((const float4*)bb)[lane];
    #pragma unroll
    for (int tt=0; tt<4; tt++){
      int t = wid*4 + tt;
      int row = row0 + t;
      float4 v = make_float4(0.f,0.f,0.f,0.f);
      if (row < 15876){
        int w = row/49, t2 = row - w*49;
        int b = w/81, wi = w - b*81;
        int wh = wi/9, ww = wi - wh*9;
        int r = t2/7, c = t2 - r*7;
        int gh = wh*7 + r, gw = ww*7 + c;
        if (gh < 60 && gw < 60)
          v = ((const float4*)(x + (size_t)(b*3600 + gh*60 + gw)*256))[lane];
      }
      float s=v.x+v.y+v.z+v.w, ss=v.x*v.x+v.y*v.y+v.z*v.z+v.w*v.w;
      #pragma unroll
      for (int off=32; off; off>>=1){ s += __shfl_xor(s,off); ss += __shfl_xor(ss,off); }
      float mean = s*(1.f/256.f);
      float var = fmaxf(ss*(1.f/256.f)-mean*mean, 0.f);
      float inv = rsqrtf(var+1e-5f);
      ushort4 pk;
      pk.x = f2bfu((v.x-mean)*inv*g4.x+b4.x);
      pk.y = f2bfu((v.y-mean)*inv*g4.y+b4.y);
      pk.z = f2bfu((v.z-mean)*inv*g4.z+b4.z);
      pk.w = f2bfu((v.w-mean)*inv*g4.w+b4.w);
      int idx = (t*256 + lane*4) ^ ((t&7)<<3);
      *(ushort4*)&xn[idx] = pk;
    }
  }
  __syncthreads();
  bf16x8 a[8];
  #pragma unroll
  for (int ks=0; ks<8; ks++){
    int idx = (li*256 + ks*32 + lg*8) ^ ((li&7)<<3);
    a[ks] = *(const bf16x8*)&xn[idx];
  }
  #pragma unroll
  for (int nt=0; nt<4; nt++){
    int ntg = wid*4 + nt;
    const bf16* wp = QWF + (size_t)ntg*4096 + lane*8;
    f32x4 acc = {0.f,0.f,0.f,0.f};
    #pragma unroll
    for (int ks=0; ks<8; ks++){
      bf16x8 bfrag = *(const bf16x8*)(wp + ks*512);
      acc = __builtin_amdgcn_mfma_f32_16x16x32_bf16(a[ks], bfrag, acc, 0, 0, 0);
    }
    int col = ntg*16 + li;
    #pragma unroll
    for (int r=0; r<4; r++){
      int row = row0 + lg*4 + r;
      if (row < 15876)
        qbuf[(size_t)row*256 + col] = f2bf(acc[r]);
    }
  }
}

// ---------------- K3: swapped-QK^T attention, single-buffer frag-order LDS -
__global__ __launch_bounds__(256) void attn_kernel(
    const bf16* __restrict__ qbuf, const bf16* __restrict__ kbuf,
    const bf16* __restrict__ vbufT, const float* __restrict__ maskbuf,
    bf16* __restrict__ obuf){
  __shared__ __align__(16) unsigned short Kls[4096];   // frag-order K, 8 KB
  __shared__ __align__(16) unsigned short VlsF[8192];  // frag-order V, 2x4 KB regions

  int tid = threadIdx.x, wid = tid>>6, lane = tid&63;
  int lg = lane>>4, li = lane&15;
  int blk = blockIdx.x;
  int w = blk >> 3, hh = blk & 7;
  int b = w/81, wi = w - b*81, wh = wi/9, ww = wi - wh*9;

  int C  = 81*wh + 3*ww - 336;     // token = kk + C
  int T0 = C & ~7;
  const bf16* kb  = kbuf  + (long long)(b*729 + T0)*256 + hh*32;
  const bf16* vbT = vbufT + (long long)(b*256 + hh*32)*736 + T0;
  const float* mk = maskbuf + wi*768;

  const bf16* ksrcA = kb + (long long)(2*wid*16 + li)*256 + lg*8;
  const bf16* ksrcB = kb + (long long)((2*wid+1)*16 + li)*256 + lg*8;
  int vrow = tid>>4, vch = tid&15;
  const bf16* vsrcA = vbT + (long long)vrow*736 + vch*8;
  const bf16* vsrcB = vbT + (long long)(vrow+16)*736 + vch*8;
  int vc_ = vch>>2, vhalf = (vch>>1)&1, vlg0 = (vch&1)*2;
  unsigned vdst0 = (unsigned)(((vc_*64 + vlg0*16     + vrow)*16 + vhalf*8) ^ (vc_<<5));
  unsigned vdst1 = (unsigned)(((vc_*64 + (vlg0+1)*16 + vrow)*16 + vhalf*8) ^ (vc_<<5));

  bf16x8 qf;
  #pragma unroll
  for (int e=0;e<8;e++) qf[e]=0;
  int qrow = wid*16 + li;
  if (qrow < 49)
    qf = *(const bf16x8*)(qbuf + ((size_t)w*49+qrow)*256 + hh*32 + lg*8);

  f32x4 o0 = {0.f,0.f,0.f,0.f}, o1 = {0.f,0.f,0.f,0.f};  // O^T: d=lg*4+r (+16), q=li
  float m = -3.0e38f, l = 0.f;

  {
    uint4 k0 = *(const uint4*)ksrcA;
    uint4 k1 = *(const uint4*)ksrcB;
    uint4 v0 = *(const uint4*)vsrcA;
    uint4 v1 = *(const uint4*)vsrcB;
    *(uint4*)&Kls[2*wid*512 + lane*8]     = k0;
    *(uint4*)&Kls[(2*wid+1)*512 + lane*8] = k1;
    *(uint2*)((char*)VlsF + vdst0)        = make_uint2(v0.x, v0.y);
    *(uint2*)((char*)VlsF + vdst1)        = make_uint2(v0.z, v0.w);
    *(uint2*)((char*)VlsF + 8192 + vdst0) = make_uint2(v1.x, v1.y);
    *(uint2*)((char*)VlsF + 8192 + vdst1) = make_uint2(v1.z, v1.w);
  }
  __syncthreads();

  for (int tile=0; tile<6; tile++){
    int jbase = tile*128;
    uint4 nk0, nk1, nv0, nv1;
    if (tile < 5){
      int jn = jbase + 128;
      nk0 = *(const uint4*)(ksrcA + (long long)jn*256);
      nk1 = *(const uint4*)(ksrcB + (long long)jn*256);
      nv0 = *(const uint4*)(vsrcA + jn);
      nv1 = *(const uint4*)(vsrcB + jn);
    }
    __builtin_amdgcn_s_setprio(1);
    f32x4 s[8];
    #pragma unroll
    for (int t=0;t<8;t++){
      bf16x8 kf = *(const bf16x8*)&Kls[t*512 + lane*8];
      f32x4 z = {0.f,0.f,0.f,0.f};
      s[t] = __builtin_amdgcn_mfma_f32_16x16x32_bf16(kf, qf, z, 0, 0, 0);
    }
    #pragma unroll
    for (int t=0;t<8;t++){
      float4 mv = *(const float4*)(mk + jbase + t*16 + lg*4);
      s[t][0] += mv.x; s[t][1] += mv.y; s[t][2] += mv.z; s[t][3] += mv.w;
    }
    float mt = -3.0e38f;
    #pragma unroll
    for (int t=0;t<8;t++)
      mt = fmaxf(mt, fmaxf(fmaxf(s[t][0], s[t][1]), fmaxf(s[t][2], s[t][3])));
    mt = fmaxf(mt, __shfl_xor(mt, 16));
    mt = fmaxf(mt, __shfl_xor(mt, 32));
    float mn = fmaxf(m, mt);
    float fac = fexp2(m - mn);
    m = mn;
    float ps = 0.f;
    #pragma unroll
    for (int t=0;t<8;t++){
      #pragma unroll
      for (int r=0;r<4;r++){
        float p = fexp2(s[t][r] - mn);
        s[t][r] = p;
        ps += p;
      }
    }
    ps += __shfl_xor(ps, 16);
    ps += __shfl_xor(ps, 32);
    l = l*fac + ps;
    #pragma unroll
    for (int r=0;r<4;r++){ o0[r] *= fac; o1[r] *= fac; }
    unsigned pk[8][2];
    #pragma unroll
    for (int t=0;t<8;t++){
      pk[t][0] = cvtpk(s[t][0], s[t][1]);
      pk[t][1] = cvtpk(s[t][2], s[t][3]);
    }
    #pragma unroll
    for (int c=0;c<4;c++){
      union { unsigned u[4]; bf16x8 v; } pb;
      pb.u[0]=pk[2*c][0];   pb.u[1]=pk[2*c][1];
      pb.u[2]=pk[2*c+1][0]; pb.u[3]=pk[2*c+1][1];
      unsigned off = (unsigned)(((c*64 + lg*16 + li)*16) ^ (c<<5));
      bf16x8 va = *(const bf16x8*)((const char*)VlsF + off);
      bf16x8 vcf = *(const bf16x8*)((const char*)VlsF + 8192 + off);
      o0 = __builtin_amdgcn_mfma_f32_16x16x32_bf16(va,  pb.v, o0, 0, 0, 0);
      o1 = __builtin_amdgcn_mfma_f32_16x16x32_bf16(vcf, pb.v, o1, 0, 0, 0);
    }
    __builtin_amdgcn_s_setprio(0);
    if (tile < 5){
      __syncthreads();
      *(uint4*)&Kls[2*wid*512 + lane*8]     = nk0;
      *(uint4*)&Kls[(2*wid+1)*512 + lane*8] = nk1;
      *(uint2*)((char*)VlsF + vdst0)        = make_uint2(nv0.x, nv0.y);
      *(uint2*)((char*)VlsF + vdst1)        = make_uint2(nv0.z, nv0.w);
      *(uint2*)((char*)VlsF + 8192 + vdst0) = make_uint2(nv1.x, nv1.y);
      *(uint2*)((char*)VlsF + 8192 + vdst1) = make_uint2(nv1.z, nv1.w);
      __syncthreads();
    }
  }

  if (qrow < 49){
    float rl = 1.f / l;
    bf16* op = obuf + ((size_t)w*49 + qrow)*256 + hh*32;
    unsigned da0 = cvtpk(o0[0]*rl, o0[1]*rl);
    unsigned da1 = cvtpk(o0[2]*rl, o0[3]*rl);
    unsigned db0 = cvtpk(o1[0]*rl, o1[1]*rl);
    unsigned db1 = cvtpk(o1[2]*rl, o1[3]*rl);
    *(uint2*)(op + lg*4)      = make_uint2(da0, da1);
    *(uint2*)(op + 16 + lg*4) = make_uint2(db0, db1);
  }
}

// ---------------- K4: per-token MFMA out-proj (993 blocks, NO LDS/barriers) -
// A-frags direct per-lane from row-linear obuf; window-reverse+crop+residual
// in the epilogue scatter.
__global__ __launch_bounds__(256) void proj_kernel(
    const bf16* __restrict__ obuf, const float* __restrict__ x,
    const bf16* __restrict__ PWF, const float* __restrict__ proj_b,
    const float* __restrict__ ls1, float* __restrict__ xobuf){
  int tid = threadIdx.x, wid = tid>>6, lane = tid&63;
  int li = lane&15, lg = lane>>4;
  int row0 = blockIdx.x * 16;
  int rowA = row0 + li; if (rowA > 15875) rowA = 15875;  // clamp: values unused
  bf16x8 a[8];
  #pragma unroll
  for (int ks=0; ks<8; ks++)
    a[ks] = *(const bf16x8*)(obuf + (size_t)rowA*256 + ks*32 + lg*8);
  float pbv[4], l1v[4];
  #pragma unroll
  for (int nt=0; nt<4; nt++){
    int col = wid*64 + nt*16 + li;
    pbv[nt] = proj_b[col];
    l1v[nt] = ls1[col];
  }
  f32x4 acc[4];
  #pragma unroll
  for (int nt=0; nt<4; nt++){
    const bf16* wp = PWF + (size_t)(wid*4 + nt)*4096 + lane*8;
    f32x4 z = {0.f,0.f,0.f,0.f};
    #pragma unroll
    for (int ks=0; ks<8; ks++){
      bf16x8 bfrag = *(const bf16x8*)(wp + ks*512);
      z = __builtin_amdgcn_mfma_f32_16x16x32_bf16(a[ks], bfrag, z, 0, 0, 0);
    }
    acc[nt] = z;
  }
  #pragma unroll
  for (int r=0; r<4; r++){
    int row = row0 + lg*4 + r;
    if (row < 15876){
      int w = row/49, t2 = row - w*49;
      int b = w/81, wi = w - b*81;
      int wh = wi/9, ww = wi - wh*9;
      int r2 = t2/7, c2 = t2 - r2*7;
      int gh = wh*7 + r2, gw = ww*7 + c2;
      if (gh < 60 && gw < 60){
        size_t base = (size_t)(b*3600 + gh*60 + gw)*256;
        #pragma unroll
        for (int nt=0; nt<4; nt++){
          int col = wid*64 + nt*16 + li;
          xobuf[base + col] = x[base + col] + l1v[nt]*(acc[nt][r] + pbv[nt]);
        }
      }
    }
  }
}

// ---------------- K5: MFMA MLP, single-shot + register B-frag prefetch ------
__global__ __launch_bounds__(256) void mlp_kernel(
    const float* __restrict__ xobuf, const float* __restrict__ g,
    const float* __restrict__ bb, const bf16* __restrict__ W1F,
    const float* __restrict__ fc1_b, const bf16* __restrict__ W2F,
    const float* __restrict__ fc2_b, const float* __restrict__ ls2,
    float* __restrict__ out){
  __shared__ __align__(16) unsigned short xn[16*256];    // swizzled bf16, 8 KB
  __shared__ __align__(16) unsigned short Hls[16*1024];  // swizzled bf16, 32 KB
  int tid = threadIdx.x, wid = tid>>6, lane = tid&63;
  int li = lane&15, lg = lane>>4;
  int tok0 = blockIdx.x * 16;
  {
    float4 g4 = ((const float4*)g)[lane];
    float4 b4 = ((const float4*)bb)[lane];
    #pragma unroll
    for (int tt=0; tt<4; tt++){
      int t = wid*4 + tt;
      float4 v = ((const float4*)(xobuf + (size_t)(tok0+t)*256))[lane];
      float s = v.x+v.y+v.z+v.w;
      float ss = v.x*v.x+v.y*v.y+v.z*v.z+v.w*v.w;
      #pragma unroll
      for (int off=32; off; off>>=1){ s += __shfl_xor(s,off); ss += __shfl_xor(ss,off); }
      float mean = s*(1.f/256.f);
      float var = fmaxf(ss*(1.f/256.f)-mean*mean, 0.f);
      float inv = rsqrtf(var+1e-5f);
      ushort4 pk;
      pk.x = f2bfu((v.x-mean)*inv*g4.x+b4.x);
      pk.y = f2bfu((v.y-mean)*inv*g4.y+b4.y);
      pk.z = f2bfu((v.z-mean)*inv*g4.z+b4.z);
      pk.w = f2bfu((v.w-mean)*inv*g4.w+b4.w);
      int idx = (t*256 + lane*4) ^ ((t&7)<<3);
      *(ushort4*)&xn[idx] = pk;
    }
  }
  __syncthreads();
  bf16x8 a1[8];
  #pragma unroll
  for (int ks=0; ks<8; ks++){
    int idx = (li*256 + ks*32 + lg*8) ^ ((li&7)<<3);
    a1[ks] = *(const bf16x8*)&xn[idx];
  }
  // ---- fc1 + GELU -> Hls: 16 col-tiles/wave, B-frags double-buffered ----
  const bf16* w1base = W1F + (size_t)(wid*16)*4096 + lane*8;
  bf16x8 bcur[8], bnxt[8];
  #pragma unroll
  for (int ks=0; ks<8; ks++) bcur[ks] = *(const bf16x8*)(w1base + ks*512);
  #pragma unroll 4
  for (int nn=0; nn<16; nn++){
    if (nn < 15){
      const bf16* wpn = w1base + (size_t)(nn+1)*4096;
      #pragma unroll
      for (int ks=0; ks<8; ks++) bnxt[ks] = *(const bf16x8*)(wpn + ks*512);
    }
    f32x4 hc = {0.f,0.f,0.f,0.f};
    #pragma unroll
    for (int ks=0; ks<8; ks++)
      hc = __builtin_amdgcn_mfma_f32_16x16x32_bf16(a1[ks], bcur[ks], hc, 0, 0, 0);
    int ntg = wid*16 + nn;
    float bias = fc1_b[ntg*16 + li];
    int col = ntg*16 + li;
    #pragma unroll
    for (int r=0; r<4; r++){
      float h = hc[r] + bias;
      float z = 0.7978845608f*(h + 0.044715f*h*h*h);   // tanh-approx GELU
      z = fminf(fmaxf(z, -15.f), 15.f);
      float e = __expf(2.f*z);
      float gv = 0.5f*h*(1.f + (e-1.f)/(e+1.f));
      int row = lg*4 + r;
      int idx = (row*1024 + col) ^ ((row&7)<<3);
      Hls[idx] = f2bfu(gv);
    }
    #pragma unroll
    for (int ks=0; ks<8; ks++) bcur[ks] = bnxt[ks];
  }
  __syncthreads();
  // ---- fc2: K=1024 in 32 chunks, h & B-frags double-buffered ----
  f32x4 oacc[4];
  #pragma unroll
  for (int nt=0; nt<4; nt++) oacc[nt] = (f32x4){0.f,0.f,0.f,0.f};
  bf16x8 hcur, hnxt, b2c[4], b2n[4];
  {
    int idx = (li*1024 + lg*8) ^ ((li&7)<<3);
    hcur = *(const bf16x8*)&Hls[idx];
    #pragma unroll
    for (int nt=0; nt<4; nt++)
      b2c[nt] = *(const bf16x8*)(W2F + ((size_t)(wid*4+nt)*32)*512 + lane*8);
  }
  #pragma unroll 4
  for (int kc=0; kc<32; kc++){
    if (kc < 31){
      int idx = (li*1024 + (kc+1)*32 + lg*8) ^ ((li&7)<<3);
      hnxt = *(const bf16x8*)&Hls[idx];
      #pragma unroll
      for (int nt=0; nt<4; nt++)
        b2n[nt] = *(const bf16x8*)(W2F + ((size_t)(wid*4+nt)*32 + kc+1)*512 + lane*8);
    }
    #pragma unroll
    for (int nt=0; nt<4; nt++)
      oacc[nt] = __builtin_amdgcn_mfma_f32_16x16x32_bf16(hcur, b2c[nt], oacc[nt], 0, 0, 0);
    hcur = hnxt;
    #pragma unroll
    for (int nt=0; nt<4; nt++) b2c[nt] = b2n[nt];
  }
  // ---- epilogue: residual + ls2 ----
  #pragma unroll
  for (int nt=0; nt<4; nt++){
    int col = wid*64 + nt*16 + li;
    float l2 = ls2[col];
    float cb = fc2_b[col];
    #pragma unroll
    for (int r=0; r<4; r++){
      int tok = tok0 + lg*4 + r;
      size_t p = (size_t)tok*256 + col;
      out[p] = xobuf[p] + l2*(oacc[nt][r] + cb);
    }
  }
}

extern "C" void kernel_launch(void* const* d_in, const int* in_sizes, int n_in,
                              void* d_out, int out_size, void* d_ws, size_t ws_size,
                              hipStream_t stream) {
  (void)in_sizes; (void)n_in; (void)out_size; (void)ws_size;
  const float* x      = (const float*)d_in[0];
  const float* y      = (const float*)d_in[1];
  const float* n1g    = (const float*)d_in[2];
  const float* n1b    = (const float*)d_in[3];
  const float* q_w    = (const float*)d_in[4];
  const float* kv_w   = (const float*)d_in[5];
  const float* proj_w = (const float*)d_in[6];
  const float* proj_b = (const float*)d_in[7];
  const float* n2g    = (const float*)d_in[8];
  const float* n2b    = (const float*)d_in[9];
  const float* fc1_w  = (const float*)d_in[10];
  const float* fc1_b  = (const float*)d_in[11];
  const float* fc2_w  = (const float*)d_in[12];
  const float* fc2_b  = (const float*)d_in[13];
  const float* ls1    = (const float*)d_in[14];
  const float* ls2    = (const float*)d_in[15];

  char* ws = (char*)d_ws;
  // Workspace (24.70 MB):
  //   qbuf  bf16[324*49*256]   @ 0          live K2..K3 (also K lo-guard: finite)
  //   kbuf  bf16[2916*256]     @ 8,128,512  live K1..K3
  //   vbufT bf16[1024*736+512] @ 9,621,504  live K1..K3 (pads zeroed by K0)
  //   obuf  bf16[324*49*256]   @ 14,745,600 live K3..K4
  //   xobuf f32 [4*3600*256]   @ 0          live K4..K5 (overlays qbuf/kbuf/vbufT)
  //   W1F @22,874,112  W2F @23,398,400  PWF @23,922,688
  //   QWF @24,053,760  KVF @24,184,832
  //   maskbuf f32[81*768]      @ 24,446,976 (ends 24,695,808)
  bf16*  qbuf  = (bf16*)(ws);
  bf16*  kbuf  = (bf16*)(ws + 8128512);
  bf16*  vbufT = (bf16*)(ws + 9621504);
  bf16*  obuf  = (bf16*)(ws + 14745600);
  float* xobuf = (float*)(ws);
  bf16*  W1F   = (bf16*)(ws + 22874112);
  bf16*  W2F   = (bf16*)(ws + 23398400);
  bf16*  PWF   = (bf16*)(ws + 23922688);
  bf16*  QWF   = (bf16*)(ws + 24053760);
  bf16*  KVF   = (bf16*)(ws + 24184832);
  float* maskbuf = (float*)(ws + 24446976);

  wt_kernel<<<3345, 256, 0, stream>>>(fc1_w, fc2_w, proj_w, q_w, kv_w,
                                      W1F, W2F, PWF, QWF, KVF, vbufT, maskbuf);
  kv_kernel<<<183, 256, 0, stream>>>(y, n1g, n1b, KVF, kbuf, vbufT);
  q_kernel<<<993, 256, 0, stream>>>(x, n1g, n1b, QWF, qbuf);
  attn_kernel<<<2592, 256, 0, stream>>>(qbuf, kbuf, vbufT, maskbuf, obuf);
  proj_kernel<<<993, 256, 0, stream>>>(obuf, x, PWF, proj_b, ls1, xobuf);
  mlp_kernel<<<900, 256, 0, stream>>>(xobuf, n2g, n2b, W1F, fc1_b, W2F, fc2_b, ls2,
                                      (float*)d_out);
}

// Round 14
// 139.057 us; speedup vs baseline: 1.5773x; 1.0394x over previous
//
#include <hip/hip_runtime.h>
#include <hip/hip_bf16.h>

typedef __hip_bfloat16 bf16;
typedef __attribute__((ext_vector_type(8))) short bf16x8;
typedef __attribute__((ext_vector_type(4))) float f32x4;

// Problem constants: B=4, H=W=60, C=256, HEADS=8, hd=32, WS=7 -> 9x9 windows/batch,
// 324 windows, 49 q/window, key window 27x27=729 gathered from the 27x27 stride-3
// grid. KEY IDENTITY: token = kk + C with C = 81*wh + 3*ww - 336 -> contiguous
// token slice; invalid keys killed by precomputed ADDITIVE mask (-30000).
// All external I/O f32; staging bf16. Softmax in log2 domain (q pre-scaled by
// hd^-0.5*log2(e); exp = v_exp_f32).
//
// Verified MFMA lane mapping (16x16x32 bf16, rounds 3-13):
//   A-frag: lane(li=lane&15, lg=lane>>4) holds A[row=li][k=lg*8+e (mod 32)]
//   B-frag: lane holds B[col=li][k=lg*8+e]
//   C/D   : [row=lg*4+r][col=li]
// Swapped QK^T: S^T = mfma(A=K, B=Q) -> lane holds S[key=t*16+lg*4+r][q=li].
// PV key<->k-slot permutation key(e)=(2c+(e>>2))*16+lg*4+(e&3) applied identically
// to the P B-frag (cvt_pk dwords) and the V A-frag layout.
// Round 14 (attn only): per-window TILE-RANGE SKIP — valid keys are row-clipped,
// kk in [kr_min*27, kr_max*27); tiles outside [t0,t1) are fully masked and are
// simply not computed (avg 5.0 of 6 tiles -> -17% attn work, numerics identical).

#define QSCALE 0.25505402616302864f  // (1/sqrt(32)) * log2(e)

__device__ __forceinline__ bf16 f2bf(float f){ return __float2bfloat16(f); }
__device__ __forceinline__ unsigned short f2bfu(float f){
  __hip_bfloat16 h = __float2bfloat16(f);
  return *(unsigned short*)&h;
}
__device__ __forceinline__ float fexp2(float x){
  float r; asm("v_exp_f32 %0, %1" : "=v"(r) : "v"(x)); return r;
}
__device__ __forceinline__ unsigned cvtpk(float lo, float hi){
  unsigned r; asm("v_cvt_pk_bf16_f32 %0, %1, %2" : "=v"(r) : "v"(lo), "v"(hi));
  return r;
}

// ---------------- K0: pack weights (fragment order) + vbufT pads + attn mask
__global__ __launch_bounds__(256) void wt_kernel(
    const float* __restrict__ fc1_w, const float* __restrict__ fc2_w,
    const float* __restrict__ proj_w, const float* __restrict__ q_w,
    const float* __restrict__ kv_w,
    bf16* __restrict__ W1F, bf16* __restrict__ W2F, bf16* __restrict__ PWF,
    bf16* __restrict__ QWF, bf16* __restrict__ KVF, bf16* __restrict__ vbufT,
    float* __restrict__ maskbuf){
  int gid = blockIdx.x*256 + threadIdx.x;
  if (gid < 262144){               // W1F: K=256 (kc<8), N=1024 (nt<64)
    int e=gid&7, lane=(gid>>3)&63, kc=(gid>>9)&7, nt=gid>>12;
    int li=lane&15, lg=lane>>4;
    W1F[gid] = f2bf(fc1_w[(size_t)(kc*32+lg*8+e)*1024 + nt*16+li]);
  } else if (gid < 524288){        // W2F: K=1024 (kc<32), N=256 (nt<16)
    int o = gid - 262144;
    int e=o&7, lane=(o>>3)&63, kc=(o>>9)&31, nt=o>>14;
    int li=lane&15, lg=lane>>4;
    W2F[o] = f2bf(fc2_w[(size_t)(kc*32+lg*8+e)*256 + nt*16+li]);
  } else if (gid < 589824){        // PWF: K=256 (kc<8), N=256 (nt<16)
    int o = gid - 524288;
    int e=o&7, lane=(o>>3)&63, kc=(o>>9)&7, nt=o>>12;
    int li=lane&15, lg=lane>>4;
    PWF[o] = f2bf(proj_w[(size_t)(kc*32+lg*8+e)*256 + nt*16+li]);
  } else if (gid < 655360){        // QWF: K=256, N=256, scaled by QSCALE
    int o = gid - 589824;
    int e=o&7, lane=(o>>3)&63, kc=(o>>9)&7, nt=o>>12;
    int li=lane&15, lg=lane>>4;
    QWF[o] = f2bf(q_w[(size_t)(kc*32+lg*8+e)*256 + nt*16+li] * QSCALE);
  } else if (gid < 786432){        // KVF: K=256, N=512 (nt<32)
    int o = gid - 655360;
    int e=o&7, lane=(o>>3)&63, kc=(o>>9)&7, nt=o>>12;
    int li=lane&15, lg=lane>>4;
    KVF[o] = f2bf(kv_w[(size_t)(kc*32+lg*8+e)*512 + nt*16+li]);
  } else {
    int idx = gid - 786432;
    if (idx < 7168){
      // vbufT row pads [row*736+729, +7): attn OOB V reads must be finite
      int row = idx/7, p = idx - row*7;
      vbufT[(size_t)row*736 + 729 + p] = f2bf(0.f);
    } else if (idx < 7680){
      vbufT[(size_t)1024*736 + (idx-7168)] = f2bf(0.f);  // hi-guard
    } else {
      // additive attn mask[81][768]: local key index -> 0 or -30000
      int o = idx - 7680;            // 0..62207
      int wi2 = o / 768, local = o - wi2*768;
      int wh2 = wi2/9, ww2 = wi2 - wh2*9;
      int C2 = 81*wh2 + 3*ww2 - 336;
      int off2 = C2 & 7;
      int kk = local - off2;
      bool valid = ((unsigned)kk < 729u);
      int kr = valid ? kk/27 : 0;
      int kc2 = kk - kr*27;
      int gr = wh2*3 - 12 + kr, gc = ww2*3 - 12 + kc2;
      valid = valid && ((unsigned)gr < 27u) && ((unsigned)gc < 27u)
                    && !(gr >= 24 && gc >= 24);
      maskbuf[(size_t)wi2*768 + local] = valid ? 0.f : -30000.f;
    }
  }
}

// ---------------- K1: MFMA LN(y)+kv proj -> kbuf (key-major) + vbufT (dim-major)
__global__ __launch_bounds__(256) void kv_kernel(
    const float* __restrict__ y, const float* __restrict__ g,
    const float* __restrict__ bb, const bf16* __restrict__ KVF,
    bf16* __restrict__ kbuf, bf16* __restrict__ vbufT){
  __shared__ __align__(16) unsigned short xn[16*256];  // swizzled bf16, 8 KB
  int tid = threadIdx.x, wid = tid>>6, lane = tid&63;
  int li = lane&15, lg = lane>>4;
  int tok0 = blockIdx.x * 16;
  {
    float4 g4 = ((const float4*)g)[lane];
    float4 b4 = ((const float4*)bb)[lane];
    #pragma unroll
    for (int tt=0; tt<4; tt++){
      int t = wid*4 + tt;
      int gtok = tok0 + t;
      float4 v = make_float4(0.f,0.f,0.f,0.f);
      if (gtok < 2916) v = ((const float4*)(y + (size_t)gtok*256))[lane];
      float s = v.x+v.y+v.z+v.w, ss = v.x*v.x+v.y*v.y+v.z*v.z+v.w*v.w;
      #pragma unroll
      for (int off=32; off; off>>=1){ s += __shfl_xor(s,off); ss += __shfl_xor(ss,off); }
      float mean = s*(1.f/256.f);
      float var  = fmaxf(ss*(1.f/256.f) - mean*mean, 0.f);
      float inv  = rsqrtf(var + 1e-5f);
      ushort4 pk;
      pk.x = f2bfu((v.x-mean)*inv*g4.x+b4.x);
      pk.y = f2bfu((v.y-mean)*inv*g4.y+b4.y);
      pk.z = f2bfu((v.z-mean)*inv*g4.z+b4.z);
      pk.w = f2bfu((v.w-mean)*inv*g4.w+b4.w);
      int idx = (t*256 + lane*4) ^ ((t&7)<<3);
      *(ushort4*)&xn[idx] = pk;
    }
  }
  __syncthreads();
  bf16x8 a[8];
  #pragma unroll
  for (int ks=0; ks<8; ks++){
    int idx = (li*256 + ks*32 + lg*8) ^ ((li&7)<<3);
    a[ks] = *(const bf16x8*)&xn[idx];
  }
  #pragma unroll
  for (int nn=0; nn<8; nn++){
    int ntg = wid*8 + nn;
    const bf16* wp = KVF + (size_t)ntg*4096 + lane*8;
    f32x4 acc = {0.f,0.f,0.f,0.f};
    #pragma unroll
    for (int ks=0; ks<8; ks++){
      bf16x8 bfrag = *(const bf16x8*)(wp + ks*512);
      acc = __builtin_amdgcn_mfma_f32_16x16x32_bf16(a[ks], bfrag, acc, 0, 0, 0);
    }
    int col = ntg*16 + li;
    #pragma unroll
    for (int r=0; r<4; r++){
      int tok = tok0 + lg*4 + r;
      if (tok < 2916){
        if (col < 256){
          kbuf[(size_t)tok*256 + col] = f2bf(acc[r]);
        } else {
          int b2 = (tok>=729) + (tok>=1458) + (tok>=2187);
          int ltok = tok - b2*729;
          vbufT[(size_t)(b2*256 + col-256)*736 + ltok] = f2bf(acc[r]);
        }
      }
    }
  }
}

// ---------------- K2: per-token MFMA LN(x)+q proj (993 blocks x 16 rows) ----
__global__ __launch_bounds__(256) void q_kernel(
    const float* __restrict__ x, const float* __restrict__ g,
    const float* __restrict__ bb, const bf16* __restrict__ QWF,
    bf16* __restrict__ qbuf){
  __shared__ __align__(16) unsigned short xn[16*256];  // swizzled bf16, 8 KB
  int tid = threadIdx.x, wid = tid>>6, lane = tid&63;
  int li = lane&15, lg = lane>>4;
  int row0 = blockIdx.x * 16;
  {
    float4 g4 = ((const float4*)g)[lane];
    float4 b4 = ((const float4*)bb)[lane];
    #pragma unroll
    for (int tt=0; tt<4; tt++){
      int t = wid*4 + tt;
      int row = row0 + t;
      float4 v = make_float4(0.f,0.f,0.f,0.f);
      if (row < 15876){
        int w = row/49, t2 = row - w*49;
        int b = w/81, wi = w - b*81;
        int wh = wi/9, ww = wi - wh*9;
        int r = t2/7, c = t2 - r*7;
        int gh = wh*7 + r, gw = ww*7 + c;
        if (gh < 60 && gw < 60)
          v = ((const float4*)(x + (size_t)(b*3600 + gh*60 + gw)*256))[lane];
      }
      float s=v.x+v.y+v.z+v.w, ss=v.x*v.x+v.y*v.y+v.z*v.z+v.w*v.w;
      #pragma unroll
      for (int off=32; off; off>>=1){ s += __shfl_xor(s,off); ss += __shfl_xor(ss,off); }
      float mean = s*(1.f/256.f);
      float var = fmaxf(ss*(1.f/256.f)-mean*mean, 0.f);
      float inv = rsqrtf(var+1e-5f);
      ushort4 pk;
      pk.x = f2bfu((v.x-mean)*inv*g4.x+b4.x);
      pk.y = f2bfu((v.y-mean)*inv*g4.y+b4.y);
      pk.z = f2bfu((v.z-mean)*inv*g4.z+b4.z);
      pk.w = f2bfu((v.w-mean)*inv*g4.w+b4.w);
      int idx = (t*256 + lane*4) ^ ((t&7)<<3);
      *(ushort4*)&xn[idx] = pk;
    }
  }
  __syncthreads();
  bf16x8 a[8];
  #pragma unroll
  for (int ks=0; ks<8; ks++){
    int idx = (li*256 + ks*32 + lg*8) ^ ((li&7)<<3);
    a[ks] = *(const bf16x8*)&xn[idx];
  }
  #pragma unroll
  for (int nt=0; nt<4; nt++){
    int ntg = wid*4 + nt;
    const bf16* wp = QWF + (size_t)ntg*4096 + lane*8;
    f32x4 acc = {0.f,0.f,0.f,0.f};
    #pragma unroll
    for (int ks=0; ks<8; ks++){
      bf16x8 bfrag = *(const bf16x8*)(wp + ks*512);
      acc = __builtin_amdgcn_mfma_f32_16x16x32_bf16(a[ks], bfrag, acc, 0, 0, 0);
    }
    int col = ntg*16 + li;
    #pragma unroll
    for (int r=0; r<4; r++){
      int row = row0 + lg*4 + r;
      if (row < 15876)
        qbuf[(size_t)row*256 + col] = f2bf(acc[r]);
    }
  }
}

// ---------------- K3: swapped-QK^T attention + per-window tile-range skip ---
__global__ __launch_bounds__(256) void attn_kernel(
    const bf16* __restrict__ qbuf, const bf16* __restrict__ kbuf,
    const bf16* __restrict__ vbufT, const float* __restrict__ maskbuf,
    bf16* __restrict__ obuf){
  __shared__ __align__(16) unsigned short Kls[4096];   // frag-order K, 8 KB
  __shared__ __align__(16) unsigned short VlsF[8192];  // frag-order V, 2x4 KB regions

  int tid = threadIdx.x, wid = tid>>6, lane = tid&63;
  int lg = lane>>4, li = lane&15;
  int blk = blockIdx.x;
  int w = blk >> 3, hh = blk & 7;
  int b = w/81, wi = w - b*81, wh = wi/9, ww = wi - wh*9;

  int C  = 81*wh + 3*ww - 336;     // token = kk + C
  int T0 = C & ~7, off = C & 7;
  // valid key rows kr in [kr_min, kr_max) -> valid kk in [kr_min*27, kr_max*27)
  // -> tiles [t0, t1) (others fully masked: skip entirely, softmax-exact).
  int kr_min = 12 - 3*wh; if (kr_min < 0) kr_min = 0;
  int kr_max = 39 - 3*wh; if (kr_max > 27) kr_max = 27;
  int t0 = (kr_min*27 + off) >> 7;
  int t1 = (kr_max*27 + off + 127) >> 7;

  const bf16* kb  = kbuf  + (long long)(b*729 + T0)*256 + hh*32;
  const bf16* vbT = vbufT + (long long)(b*256 + hh*32)*736 + T0;
  const float* mk = maskbuf + wi*768;

  const bf16* ksrcA = kb + (long long)(2*wid*16 + li)*256 + lg*8;
  const bf16* ksrcB = kb + (long long)((2*wid+1)*16 + li)*256 + lg*8;
  int vrow = tid>>4, vch = tid&15;
  const bf16* vsrcA = vbT + (long long)vrow*736 + vch*8;
  const bf16* vsrcB = vbT + (long long)(vrow+16)*736 + vch*8;
  int vc_ = vch>>2, vhalf = (vch>>1)&1, vlg0 = (vch&1)*2;
  unsigned vdst0 = (unsigned)(((vc_*64 + vlg0*16     + vrow)*16 + vhalf*8) ^ (vc_<<5));
  unsigned vdst1 = (unsigned)(((vc_*64 + (vlg0+1)*16 + vrow)*16 + vhalf*8) ^ (vc_<<5));

  bf16x8 qf;
  #pragma unroll
  for (int e=0;e<8;e++) qf[e]=0;
  int qrow = wid*16 + li;
  if (qrow < 49)
    qf = *(const bf16x8*)(qbuf + ((size_t)w*49+qrow)*256 + hh*32 + lg*8);

  f32x4 o0 = {0.f,0.f,0.f,0.f}, o1 = {0.f,0.f,0.f,0.f};  // O^T: d=lg*4+r (+16), q=li
  float m = -3.0e38f, l = 0.f;

  {
    int j0 = t0*128;
    uint4 k0 = *(const uint4*)(ksrcA + (long long)j0*256);
    uint4 k1 = *(const uint4*)(ksrcB + (long long)j0*256);
    uint4 v0 = *(const uint4*)(vsrcA + j0);
    uint4 v1 = *(const uint4*)(vsrcB + j0);
    *(uint4*)&Kls[2*wid*512 + lane*8]     = k0;
    *(uint4*)&Kls[(2*wid+1)*512 + lane*8] = k1;
    *(uint2*)((char*)VlsF + vdst0)        = make_uint2(v0.x, v0.y);
    *(uint2*)((char*)VlsF + vdst1)        = make_uint2(v0.z, v0.w);
    *(uint2*)((char*)VlsF + 8192 + vdst0) = make_uint2(v1.x, v1.y);
    *(uint2*)((char*)VlsF + 8192 + vdst1) = make_uint2(v1.z, v1.w);
  }
  __syncthreads();

  for (int tile=t0; tile<t1; tile++){
    int jbase = tile*128;
    uint4 nk0, nk1, nv0, nv1;
    if (tile+1 < t1){
      int jn = jbase + 128;
      nk0 = *(const uint4*)(ksrcA + (long long)jn*256);
      nk1 = *(const uint4*)(ksrcB + (long long)jn*256);
      nv0 = *(const uint4*)(vsrcA + jn);
      nv1 = *(const uint4*)(vsrcB + jn);
    }
    __builtin_amdgcn_s_setprio(1);
    f32x4 s[8];
    #pragma unroll
    for (int t=0;t<8;t++){
      bf16x8 kf = *(const bf16x8*)&Kls[t*512 + lane*8];
      f32x4 z = {0.f,0.f,0.f,0.f};
      s[t] = __builtin_amdgcn_mfma_f32_16x16x32_bf16(kf, qf, z, 0, 0, 0);
    }
    #pragma unroll
    for (int t=0;t<8;t++){
      float4 mv = *(const float4*)(mk + jbase + t*16 + lg*4);
      s[t][0] += mv.x; s[t][1] += mv.y; s[t][2] += mv.z; s[t][3] += mv.w;
    }
    // max over 32 lane-local values, nested triples (v_max3-friendly)
    float m0 = fmaxf(fmaxf(s[0][0], s[0][1]), fmaxf(s[0][2], s[0][3]));
    float m1 = fmaxf(fmaxf(s[1][0], s[1][1]), fmaxf(s[1][2], s[1][3]));
    float m2 = fmaxf(fmaxf(s[2][0], s[2][1]), fmaxf(s[2][2], s[2][3]));
    float m3 = fmaxf(fmaxf(s[3][0], s[3][1]), fmaxf(s[3][2], s[3][3]));
    float m4 = fmaxf(fmaxf(s[4][0], s[4][1]), fmaxf(s[4][2], s[4][3]));
    float m5 = fmaxf(fmaxf(s[5][0], s[5][1]), fmaxf(s[5][2], s[5][3]));
    float m6 = fmaxf(fmaxf(s[6][0], s[6][1]), fmaxf(s[6][2], s[6][3]));
    float m7 = fmaxf(fmaxf(s[7][0], s[7][1]), fmaxf(s[7][2], s[7][3]));
    float mt = fmaxf(fmaxf(fmaxf(m0, m1), fmaxf(m2, m3)),
                     fmaxf(fmaxf(m4, m5), fmaxf(m6, m7)));
    mt = fmaxf(mt, __shfl_xor(mt, 16));
    mt = fmaxf(mt, __shfl_xor(mt, 32));
    float mn = fmaxf(m, mt);
    float fac = fexp2(m - mn);
    m = mn;
    float ps = 0.f;
    #pragma unroll
    for (int t=0;t<8;t++){
      #pragma unroll
      for (int r=0;r<4;r++){
        float p = fexp2(s[t][r] - mn);
        s[t][r] = p;
        ps += p;
      }
    }
    ps += __shfl_xor(ps, 16);
    ps += __shfl_xor(ps, 32);
    l = l*fac + ps;
    #pragma unroll
    for (int r=0;r<4;r++){ o0[r] *= fac; o1[r] *= fac; }
    unsigned pk[8][2];
    #pragma unroll
    for (int t=0;t<8;t++){
      pk[t][0] = cvtpk(s[t][0], s[t][1]);
      pk[t][1] = cvtpk(s[t][2], s[t][3]);
    }
    #pragma unroll
    for (int c=0;c<4;c++){
      union { unsigned u[4]; bf16x8 v; } pb;
      pb.u[0]=pk[2*c][0];   pb.u[1]=pk[2*c][1];
      pb.u[2]=pk[2*c+1][0]; pb.u[3]=pk[2*c+1][1];
      unsigned offb = (unsigned)(((c*64 + lg*16 + li)*16) ^ (c<<5));
      bf16x8 va = *(const bf16x8*)((const char*)VlsF + offb);
      bf16x8 vcf = *(const bf16x8*)((const char*)VlsF + 8192 + offb);
      o0 = __builtin_amdgcn_mfma_f32_16x16x32_bf16(va,  pb.v, o0, 0, 0, 0);
      o1 = __builtin_amdgcn_mfma_f32_16x16x32_bf16(vcf, pb.v, o1, 0, 0, 0);
    }
    __builtin_amdgcn_s_setprio(0);
    if (tile+1 < t1){
      __syncthreads();
      *(uint4*)&Kls[2*wid*512 + lane*8]     = nk0;
      *(uint4*)&Kls[(2*wid+1)*512 + lane*8] = nk1;
      *(uint2*)((char*)VlsF + vdst0)        = make_uint2(nv0.x, nv0.y);
      *(uint2*)((char*)VlsF + vdst1)        = make_uint2(nv0.z, nv0.w);
      *(uint2*)((char*)VlsF + 8192 + vdst0) = make_uint2(nv1.x, nv1.y);
      *(uint2*)((char*)VlsF + 8192 + vdst1) = make_uint2(nv1.z, nv1.w);
      __syncthreads();
    }
  }

  if (qrow < 49){
    float rl = 1.f / l;
    bf16* op = obuf + ((size_t)w*49 + qrow)*256 + hh*32;
    unsigned da0 = cvtpk(o0[0]*rl, o0[1]*rl);
    unsigned da1 = cvtpk(o0[2]*rl, o0[3]*rl);
    unsigned db0 = cvtpk(o1[0]*rl, o1[1]*rl);
    unsigned db1 = cvtpk(o1[2]*rl, o1[3]*rl);
    *(uint2*)(op + lg*4)      = make_uint2(da0, da1);
    *(uint2*)(op + 16 + lg*4) = make_uint2(db0, db1);
  }
}

// ---------------- K4: per-token MFMA out-proj (993 blocks, NO LDS/barriers) -
__global__ __launch_bounds__(256) void proj_kernel(
    const bf16* __restrict__ obuf, const float* __restrict__ x,
    const bf16* __restrict__ PWF, const float* __restrict__ proj_b,
    const float* __restrict__ ls1, float* __restrict__ xobuf){
  int tid = threadIdx.x, wid = tid>>6, lane = tid&63;
  int li = lane&15, lg = lane>>4;
  int row0 = blockIdx.x * 16;
  int rowA = row0 + li; if (rowA > 15875) rowA = 15875;  // clamp: values unused
  bf16x8 a[8];
  #pragma unroll
  for (int ks=0; ks<8; ks++)
    a[ks] = *(const bf16x8*)(obuf + (size_t)rowA*256 + ks*32 + lg*8);
  float pbv[4], l1v[4];
  #pragma unroll
  for (int nt=0; nt<4; nt++){
    int col = wid*64 + nt*16 + li;
    pbv[nt] = proj_b[col];
    l1v[nt] = ls1[col];
  }
  f32x4 acc[4];
  #pragma unroll
  for (int nt=0; nt<4; nt++){
    const bf16* wp = PWF + (size_t)(wid*4 + nt)*4096 + lane*8;
    f32x4 z = {0.f,0.f,0.f,0.f};
    #pragma unroll
    for (int ks=0; ks<8; ks++){
      bf16x8 bfrag = *(const bf16x8*)(wp + ks*512);
      z = __builtin_amdgcn_mfma_f32_16x16x32_bf16(a[ks], bfrag, z, 0, 0, 0);
    }
    acc[nt] = z;
  }
  #pragma unroll
  for (int r=0; r<4; r++){
    int row = row0 + lg*4 + r;
    if (row < 15876){
      int w = row/49, t2 = row - w*49;
      int b = w/81, wi = w - b*81;
      int wh = wi/9, ww = wi - wh*9;
      int r2 = t2/7, c2 = t2 - r2*7;
      int gh = wh*7 + r2, gw = ww*7 + c2;
      if (gh < 60 && gw < 60){
        size_t base = (size_t)(b*3600 + gh*60 + gw)*256;
        #pragma unroll
        for (int nt=0; nt<4; nt++){
          int col = wid*64 + nt*16 + li;
          xobuf[base + col] = x[base + col] + l1v[nt]*(acc[nt][r] + pbv[nt]);
        }
      }
    }
  }
}

// ---------------- K5: MFMA MLP, single-shot + register B-frag prefetch ------
__global__ __launch_bounds__(256) void mlp_kernel(
    const float* __restrict__ xobuf, const float* __restrict__ g,
    const float* __restrict__ bb, const bf16* __restrict__ W1F,
    const float* __restrict__ fc1_b, const bf16* __restrict__ W2F,
    const float* __restrict__ fc2_b, const float* __restrict__ ls2,
    float* __restrict__ out){
  __shared__ __align__(16) unsigned short xn[16*256];    // swizzled bf16, 8 KB
  __shared__ __align__(16) unsigned short Hls[16*1024];  // swizzled bf16, 32 KB
  int tid = threadIdx.x, wid = tid>>6, lane = tid&63;
  int li = lane&15, lg = lane>>4;
  int tok0 = blockIdx.x * 16;
  {
    float4 g4 = ((const float4*)g)[lane];
    float4 b4 = ((const float4*)bb)[lane];
    #pragma unroll
    for (int tt=0; tt<4; tt++){
      int t = wid*4 + tt;
      float4 v = ((const float4*)(xobuf + (size_t)(tok0+t)*256))[lane];
      float s = v.x+v.y+v.z+v.w;
      float ss = v.x*v.x+v.y*v.y+v.z*v.z+v.w*v.w;
      #pragma unroll
      for (int off=32; off; off>>=1){ s += __shfl_xor(s,off); ss += __shfl_xor(ss,off); }
      float mean = s*(1.f/256.f);
      float var = fmaxf(ss*(1.f/256.f)-mean*mean, 0.f);
      float inv = rsqrtf(var+1e-5f);
      ushort4 pk;
      pk.x = f2bfu((v.x-mean)*inv*g4.x+b4.x);
      pk.y = f2bfu((v.y-mean)*inv*g4.y+b4.y);
      pk.z = f2bfu((v.z-mean)*inv*g4.z+b4.z);
      pk.w = f2bfu((v.w-mean)*inv*g4.w+b4.w);
      int idx = (t*256 + lane*4) ^ ((t&7)<<3);
      *(ushort4*)&xn[idx] = pk;
    }
  }
  __syncthreads();
  bf16x8 a1[8];
  #pragma unroll
  for (int ks=0; ks<8; ks++){
    int idx = (li*256 + ks*32 + lg*8) ^ ((li&7)<<3);
    a1[ks] = *(const bf16x8*)&xn[idx];
  }
  // ---- fc1 + GELU -> Hls: 16 col-tiles/wave, B-frags double-buffered ----
  const bf16* w1base = W1F + (size_t)(wid*16)*4096 + lane*8;
  bf16x8 bcur[8], bnxt[8];
  #pragma unroll
  for (int ks=0; ks<8; ks++) bcur[ks] = *(const bf16x8*)(w1base + ks*512);
  #pragma unroll 4
  for (int nn=0; nn<16; nn++){
    if (nn < 15){
      const bf16* wpn = w1base + (size_t)(nn+1)*4096;
      #pragma unroll
      for (int ks=0; ks<8; ks++) bnxt[ks] = *(const bf16x8*)(wpn + ks*512);
    }
    f32x4 hc = {0.f,0.f,0.f,0.f};
    #pragma unroll
    for (int ks=0; ks<8; ks++)
      hc = __builtin_amdgcn_mfma_f32_16x16x32_bf16(a1[ks], bcur[ks], hc, 0, 0, 0);
    int ntg = wid*16 + nn;
    float bias = fc1_b[ntg*16 + li];
    int col = ntg*16 + li;
    #pragma unroll
    for (int r=0; r<4; r++){
      float h = hc[r] + bias;
      float z = 0.7978845608f*(h + 0.044715f*h*h*h);   // tanh-approx GELU
      z = fminf(fmaxf(z, -15.f), 15.f);
      float e = __expf(2.f*z);
      float gv = 0.5f*h*(1.f + (e-1.f)/(e+1.f));
      int row = lg*4 + r;
      int idx = (row*1024 + col) ^ ((row&7)<<3);
      Hls[idx] = f2bfu(gv);
    }
    #pragma unroll
    for (int ks=0; ks<8; ks++) bcur[ks] = bnxt[ks];
  }
  __syncthreads();
  // ---- fc2: K=1024 in 32 chunks, h & B-frags double-buffered ----
  f32x4 oacc[4];
  #pragma unroll
  for (int nt=0; nt<4; nt++) oacc[nt] = (f32x4){0.f,0.f,0.f,0.f};
  bf16x8 hcur, hnxt, b2c[4], b2n[4];
  {
    int idx = (li*1024 + lg*8) ^ ((li&7)<<3);
    hcur = *(const bf16x8*)&Hls[idx];
    #pragma unroll
    for (int nt=0; nt<4; nt++)
      b2c[nt] = *(const bf16x8*)(W2F + ((size_t)(wid*4+nt)*32)*512 + lane*8);
  }
  #pragma unroll 4
  for (int kc=0; kc<32; kc++){
    if (kc < 31){
      int idx = (li*1024 + (kc+1)*32 + lg*8) ^ ((li&7)<<3);
      hnxt = *(const bf16x8*)&Hls[idx];
      #pragma unroll
      for (int nt=0; nt<4; nt++)
        b2n[nt] = *(const bf16x8*)(W2F + ((size_t)(wid*4+nt)*32 + kc+1)*512 + lane*8);
    }
    #pragma unroll
    for (int nt=0; nt<4; nt++)
      oacc[nt] = __builtin_amdgcn_mfma_f32_16x16x32_bf16(hcur, b2c[nt], oacc[nt], 0, 0, 0);
    hcur = hnxt;
    #pragma unroll
    for (int nt=0; nt<4; nt++) b2c[nt] = b2n[nt];
  }
  // ---- epilogue: residual + ls2 ----
  #pragma unroll
  for (int nt=0; nt<4; nt++){
    int col = wid*64 + nt*16 + li;
    float l2 = ls2[col];
    float cb = fc2_b[col];
    #pragma unroll
    for (int r=0; r<4; r++){
      int tok = tok0 + lg*4 + r;
      size_t p = (size_t)tok*256 + col;
      out[p] = xobuf[p] + l2*(oacc[nt][r] + cb);
    }
  }
}

extern "C" void kernel_launch(void* const* d_in, const int* in_sizes, int n_in,
                              void* d_out, int out_size, void* d_ws, size_t ws_size,
                              hipStream_t stream) {
  (void)in_sizes; (void)n_in; (void)out_size; (void)ws_size;
  const float* x      = (const float*)d_in[0];
  const float* y      = (const float*)d_in[1];
  const float* n1g    = (const float*)d_in[2];
  const float* n1b    = (const float*)d_in[3];
  const float* q_w    = (const float*)d_in[4];
  const float* kv_w   = (const float*)d_in[5];
  const float* proj_w = (const float*)d_in[6];
  const float* proj_b = (const float*)d_in[7];
  const float* n2g    = (const float*)d_in[8];
  const float* n2b    = (const float*)d_in[9];
  const float* fc1_w  = (const float*)d_in[10];
  const float* fc1_b  = (const float*)d_in[11];
  const float* fc2_w  = (const float*)d_in[12];
  const float* fc2_b  = (const float*)d_in[13];
  const float* ls1    = (const float*)d_in[14];
  const float* ls2    = (const float*)d_in[15];

  char* ws = (char*)d_ws;
  // Workspace (24.70 MB):
  //   qbuf  bf16[324*49*256]   @ 0          live K2..K3 (also K lo-guard: finite)
  //   kbuf  bf16[2916*256]     @ 8,128,512  live K1..K3
  //   vbufT bf16[1024*736+512] @ 9,621,504  live K1..K3 (pads zeroed by K0)
  //   obuf  bf16[324*49*256]   @ 14,745,600 live K3..K4
  //   xobuf f32 [4*3600*256]   @ 0          live K4..K5 (overlays qbuf/kbuf/vbufT)
  //   W1F @22,874,112  W2F @23,398,400  PWF @23,922,688
  //   QWF @24,053,760  KVF @24,184,832
  //   maskbuf f32[81*768]      @ 24,446,976 (ends 24,695,808)
  bf16*  qbuf  = (bf16*)(ws);
  bf16*  kbuf  = (bf16*)(ws + 8128512);
  bf16*  vbufT = (bf16*)(ws + 9621504);
  bf16*  obuf  = (bf16*)(ws + 14745600);
  float* xobuf = (float*)(ws);
  bf16*  W1F   = (bf16*)(ws + 22874112);
  bf16*  W2F   = (bf16*)(ws + 23398400);
  bf16*  PWF   = (bf16*)(ws + 23922688);
  bf16*  QWF   = (bf16*)(ws + 24053760);
  bf16*  KVF   = (bf16*)(ws + 24184832);
  float* maskbuf = (float*)(ws + 24446976);

  wt_kernel<<<3345, 256, 0, stream>>>(fc1_w, fc2_w, proj_w, q_w, kv_w,
                                      W1F, W2F, PWF, QWF, KVF, vbufT, maskbuf);
  kv_kernel<<<183, 256, 0, stream>>>(y, n1g, n1b, KVF, kbuf, vbufT);
  q_kernel<<<993, 256, 0, stream>>>(x, n1g, n1b, QWF, qbuf);
  attn_kernel<<<2592, 256, 0, stream>>>(qbuf, kbuf, vbufT, maskbuf, obuf);
  proj_kernel<<<993, 256, 0, stream>>>(obuf, x, PWF, proj_b, ls1, xobuf);
  mlp_kernel<<<900, 256, 0, stream>>>(xobuf, n2g, n2b, W1F, fc1_b, W2F, fc2_b, ls2,
                                      (float*)d_out);
}